// Round 9
// baseline (779.468 us; speedup 1.0000x reference)
//
#include <hip/hip_runtime.h>
#include <math.h>

#define HID 64
#define BKT_W 256          // nodes per bucket (power of 2)
#define BKT_SHIFT 8
#define MAX_BKT 512        // supports N <= 131072
#define EPB 4096           // edges per binA block
#define EPH 16384          // edges per bhist block

__device__ __forceinline__ unsigned short f2bf(float x) {
    unsigned int b = __float_as_uint(x);
    unsigned int r = (b + 0x7FFFu + ((b >> 16) & 1u)) >> 16;   // RNE
    return (unsigned short)r;
}
__device__ __forceinline__ float bf2f(unsigned short u) {
    return __uint_as_float((unsigned int)u << 16);
}

// ---------------- bucket-level histogram ----------------
__global__ __launch_bounds__(256) void k_bhist(const int* __restrict__ col,
                                               int* __restrict__ bkt_cnt, int E, int nbkt) {
    __shared__ int h[MAX_BKT];
    int t = threadIdx.x;
    for (int b = t; b < nbkt; b += 256) h[b] = 0;
    __syncthreads();
    int e0 = blockIdx.x * EPH;
    int e1 = min(e0 + EPH, E);
    for (int e = e0 + t; e < e1; e += 256)
        atomicAdd(&h[col[e] >> BKT_SHIFT], 1);
    __syncthreads();
    for (int b = t; b < nbkt; b += 256)
        if (h[b]) atomicAdd(&bkt_cnt[b], h[b]);
}

__global__ void k_bscan(const int* __restrict__ bkt_cnt, int* __restrict__ bkt_base, int nbkt) {
    int run = 0;
    for (int b = 0; b < nbkt; ++b) { bkt_base[b] = run; run += bkt_cnt[b]; }
    bkt_base[nbkt] = run;
}

__global__ void k_bcinit(const int* __restrict__ bkt_base, int* __restrict__ bcursor, int nbkt) {
    int b = blockIdx.x * blockDim.x + threadIdx.x;
    if (b < nbkt) bcursor[b] = bkt_base[b];
}

// pass A: bin edges into bucket-contiguous packed (row<<8 | col&255) words
__global__ __launch_bounds__(256) void k_binA(const int* __restrict__ row,
                                              const int* __restrict__ col,
                                              int* __restrict__ bcursor,
                                              unsigned int* __restrict__ pairs,
                                              int E, int nbkt) {
    __shared__ int hist[MAX_BKT];
    __shared__ int base[MAX_BKT];
    int t = threadIdx.x;
    for (int b = t; b < nbkt; b += 256) hist[b] = 0;
    __syncthreads();
    int e0 = blockIdx.x * EPB;
    int myc[16], myr[16], myoff[16];
    #pragma unroll
    for (int i = 0; i < 16; ++i) {
        int e = e0 + t + i * 256;
        if (e < E) {
            myc[i] = col[e];
            myr[i] = row[e];
            myoff[i] = atomicAdd(&hist[myc[i] >> BKT_SHIFT], 1);
        }
    }
    __syncthreads();
    for (int b = t; b < nbkt; b += 256) {
        int h = hist[b];
        base[b] = h ? atomicAdd(&bcursor[b], h) : 0;
    }
    __syncthreads();
    #pragma unroll
    for (int i = 0; i < 16; ++i) {
        int e = e0 + t + i * 256;
        if (e < E) {
            int bk = myc[i] >> BKT_SHIFT;
            pairs[base[bk] + myoff[i]] =
                ((unsigned int)myr[i] << BKT_SHIFT) | (unsigned int)(myc[i] & (BKT_W - 1));
        }
    }
}

// pass B: per bucket — per-node counts in LDS, LDS scan -> rowptr + dinv, scatter srcs
__global__ __launch_bounds__(256) void k_binB(const unsigned int* __restrict__ pairs,
                                              const int* __restrict__ bkt_base,
                                              int* __restrict__ rowptr,
                                              int* __restrict__ srcs,
                                              float* __restrict__ dinv,
                                              int n, int E) {
    __shared__ int cnt[BKT_W];
    __shared__ int s[BKT_W];
    __shared__ int lcur[BKT_W];
    int b = blockIdx.x, t = threadIdx.x;
    int n0 = b << BKT_SHIFT;
    int n1 = min(n0 + BKT_W, n);
    int s0 = bkt_base[b], s1 = bkt_base[b + 1];
    cnt[t] = 0;
    __syncthreads();
    for (int i = s0 + t; i < s1; i += 256)
        atomicAdd(&cnt[pairs[i] & (BKT_W - 1)], 1);
    __syncthreads();
    int v = cnt[t];
    s[t] = v;
    __syncthreads();
    #pragma unroll
    for (int off = 1; off < BKT_W; off <<= 1) {
        int tv = (t >= off) ? s[t - off] : 0;
        __syncthreads();
        s[t] += tv;
        __syncthreads();
    }
    int ex = s[t] - v;
    if (t < n1 - n0) {
        rowptr[n0 + t] = s0 + ex;
        dinv[n0 + t] = rsqrtf((float)(v + 1));   // +1 self-loop
    }
    lcur[t] = s0 + ex;
    __syncthreads();
    for (int i = s0 + t; i < s1; i += 256) {
        unsigned int p = pairs[i];
        int pos = atomicAdd(&lcur[p & (BKT_W - 1)], 1);
        srcs[pos] = (int)(p >> BKT_SHIFT);
    }
    if (n1 == n && t == 0) rowptr[n] = E;
}

// ---------------- GEMM: outS[pass][i][c16] = bf16( dinv[i] * (A@W)[i][c] ) ----------------
// channel-split layout: pass = c>>4, slot = c&15
__global__ __launch_bounds__(256) void k_gemm(const float* __restrict__ A,
                                              const float* __restrict__ W,
                                              const float* __restrict__ dinv,
                                              unsigned short* __restrict__ outS,
                                              int n, int K) {
    __shared__ float sA[32][64];
    __shared__ float sW[32][64];
    int t = threadIdx.x;
    int m0 = blockIdx.x * 64;
    int tm = t >> 4, tn = t & 15;
    float acc[4][4] = {};

    int arow = t >> 2;
    int akb  = (t & 3) * 8;
    int wrow = t >> 3;
    int wcb  = (t & 7) * 8;

    for (int k0 = 0; k0 < K; k0 += 32) {
        int node = m0 + arow;
        if (node < n && k0 + akb + 7 < K) {
            const float4* p = (const float4*)(A + (size_t)node * K + k0 + akb);
            float4 v0 = p[0], v1 = p[1];
            sA[akb + 0][arow] = v0.x; sA[akb + 1][arow] = v0.y;
            sA[akb + 2][arow] = v0.z; sA[akb + 3][arow] = v0.w;
            sA[akb + 4][arow] = v1.x; sA[akb + 5][arow] = v1.y;
            sA[akb + 6][arow] = v1.z; sA[akb + 7][arow] = v1.w;
        } else {
            for (int u = 0; u < 8; ++u) {
                int k = k0 + akb + u;
                sA[akb + u][arow] = (node < n && k < K) ? A[(size_t)node * K + k] : 0.0f;
            }
        }
        {
            int k = k0 + wrow;
            if (k < K) {
                const float4* p = (const float4*)(W + (size_t)k * HID + wcb);
                *(float4*)&sW[wrow][wcb]     = p[0];
                *(float4*)&sW[wrow][wcb + 4] = p[1];
            } else {
                float4 z = {0.f, 0.f, 0.f, 0.f};
                *(float4*)&sW[wrow][wcb]     = z;
                *(float4*)&sW[wrow][wcb + 4] = z;
            }
        }
        __syncthreads();
        #pragma unroll
        for (int kk = 0; kk < 32; ++kk) {
            float4 av = *(const float4*)&sA[kk][tm * 4];
            float4 wv = *(const float4*)&sW[kk][tn * 4];
            const float* ap = &av.x;
            #pragma unroll
            for (int i = 0; i < 4; ++i) {
                float a = ap[i];
                acc[i][0] = fmaf(a, wv.x, acc[i][0]);
                acc[i][1] = fmaf(a, wv.y, acc[i][1]);
                acc[i][2] = fmaf(a, wv.z, acc[i][2]);
                acc[i][3] = fmaf(a, wv.w, acc[i][3]);
            }
        }
        __syncthreads();
    }
    // channels for this thread: tn*4 .. tn*4+3  -> pass = tn>>2, slot0 = (tn&3)*4
    size_t pbase = (size_t)(tn >> 2) * n * 16;
    int slot0 = (tn & 3) * 4;
    #pragma unroll
    for (int i = 0; i < 4; ++i) {
        int node = m0 + tm * 4 + i;
        if (node < n) {
            float d = dinv[node];
            ushort4 o;
            o.x = f2bf(acc[i][0] * d);
            o.y = f2bf(acc[i][1] * d);
            o.z = f2bf(acc[i][2] * d);
            o.w = f2bf(acc[i][3] * d);
            *(ushort4*)(outS + pbase + (size_t)node * 16 + slot0) = o;
        }
    }
}

// ---------------- gather aggregation, one 16-channel pass ----------------
// wave = 1 node; lane = edge_slot*16 + channel; 4 edges in flight, 2-deep unroll.
// bp = bufS + p*N*16, bias_p = bias + p*16, out_p = out + p*16 (stride HID)
__global__ __launch_bounds__(256) void k_agg(const unsigned short* __restrict__ bp,
                                             const int* __restrict__ rowptr,
                                             const int* __restrict__ srcs,
                                             const float* __restrict__ dinv,
                                             const float* __restrict__ bias_p,
                                             float* __restrict__ out_p, int n) {
    int node = blockIdx.x * 4 + (threadIdx.x >> 6);
    if (node >= n) return;
    int lane = threadIdx.x & 63;
    int e4 = lane >> 4, c = lane & 15;
    float a = 0.f;
    if (e4 == 0) a = bf2f(bp[(size_t)node * 16 + c]);   // self-loop term
    int s = rowptr[node], e = rowptr[node + 1];
    int k = s + e4;
    for (; k + 4 < e; k += 8) {
        int r0 = srcs[k];
        int r1 = srcs[k + 4];
        float v0 = bf2f(bp[(size_t)r0 * 16 + c]);
        float v1 = bf2f(bp[(size_t)r1 * 16 + c]);
        a += v0 + v1;
    }
    if (k < e) a += bf2f(bp[(size_t)srcs[k] * 16 + c]);
    a += __shfl_xor(a, 16);
    a += __shfl_xor(a, 32);
    if (lane < 16) {
        float v = fmaf(a, dinv[node], bias_p[c]);
        out_p[(size_t)node * HID + c] = v > 0.f ? v : 0.f;
    }
}

// ---------------- pooling ----------------
#define PCHUNK 128
__global__ void k_pool(const float* __restrict__ h, const int* __restrict__ batch,
                       const int* __restrict__ ne_arr,
                       float* ent_sum, float* all_sum, float* ent_cnt, float* node_cnt,
                       int n) {
    int wave = blockIdx.x * (blockDim.x >> 6) + (threadIdx.x >> 6);
    int j = threadIdx.x & 63;
    int i0 = wave * PCHUNK;
    if (i0 >= n) return;
    int iend = min(i0 + PCHUNK, n);
    int g = batch[i0];
    int ne = ne_arr[g];
    float ea = 0.f, aa = 0.f, ec = 0.f, nc = 0.f;
    for (int i = i0; i < iend; ++i) {
        int gi = batch[i];
        if (gi != g) {
            atomicAdd(&all_sum[g * HID + j], aa);
            atomicAdd(&ent_sum[g * HID + j], ea);
            if (j == 0) { atomicAdd(&node_cnt[g], nc); atomicAdd(&ent_cnt[g], ec); }
            g = gi; ne = ne_arr[g];
            ea = aa = ec = nc = 0.f;
        }
        float v = h[(size_t)i * HID + j];
        aa += v; nc += 1.f;
        if (i < ne) { ea += v; ec += 1.f; }
    }
    atomicAdd(&all_sum[g * HID + j], aa);
    atomicAdd(&ent_sum[g * HID + j], ea);
    if (j == 0) { atomicAdd(&node_cnt[g], nc); atomicAdd(&ent_cnt[g], ec); }
}

// ---------------- head ----------------
__global__ void k_final(const float* __restrict__ ent_sum, const float* __restrict__ all_sum,
                        const float* __restrict__ ent_cnt, const float* __restrict__ node_cnt,
                        const float* __restrict__ Wlin, const float* __restrict__ blin,
                        float* __restrict__ out, int ncls) {
    int g = blockIdx.x, j = threadIdx.x;
    __shared__ float pooled[HID];
    __shared__ float logits[32];
    float ec = ent_cnt[g];
    float p;
    if (ec > 0.0f)
        p = ent_sum[g * HID + j] / (ec + 1e-6f);
    else
        p = all_sum[g * HID + j] / node_cnt[g];
    pooled[j] = p;
    __syncthreads();
    if (j < ncls) {
        float acc = blin[j];
        for (int k = 0; k < HID; ++k)
            acc = fmaf(pooled[k], Wlin[k * ncls + j], acc);
        logits[j] = acc;
    }
    __syncthreads();
    if (j < ncls) {
        float m = -INFINITY;
        for (int c = 0; c < ncls; ++c) m = fmaxf(m, logits[c]);
        float s = 0.0f;
        for (int c = 0; c < ncls; ++c) s += expf(logits[c] - m);
        out[g * ncls + j] = logits[j] - m - logf(s);
    }
}

extern "C" void kernel_launch(void* const* d_in, const int* in_sizes, int n_in,
                              void* d_out, int out_size, void* d_ws, size_t ws_size,
                              hipStream_t stream) {
    const float* x          = (const float*)d_in[0];
    const int*   ei         = (const int*)d_in[1];
    const int*   batch      = (const int*)d_in[2];
    const int*   num_entity = (const int*)d_in[3];
    const float* W1         = (const float*)d_in[4];
    const float* b1         = (const float*)d_in[5];
    const float* W2         = (const float*)d_in[6];
    const float* b2         = (const float*)d_in[7];
    const float* Wlin       = (const float*)d_in[8];
    const float* blin       = (const float*)d_in[9];
    float* out = (float*)d_out;

    int N = in_sizes[2];
    int E = in_sizes[1] / 2;
    int K = in_sizes[0] / N;      // 300
    int G = in_sizes[3];
    int NCLS = in_sizes[9];

    const int* row = ei;          // source
    const int* col = ei + E;      // target

    // ---- workspace layout ----
    char* wsb = (char*)d_ws;
    size_t off = 0;
    auto take = [&](size_t bytes) -> void* {
        void* p = wsb + off;
        off += (bytes + 255) & ~(size_t)255;
        return p;
    };
    int*   rowptr   = (int*)take((size_t)(N + 1) * 4);
    float* dinv     = (float*)take((size_t)N * 4);
    int*   bkt_cnt  = (int*)take(MAX_BKT * 4);
    int*   bkt_base = (int*)take((MAX_BKT + 1) * 4);
    int*   bcursor  = (int*)take(MAX_BKT * 4);
    int*   srcs     = (int*)take((size_t)E * 4);
    unsigned short* bufS = (unsigned short*)take((size_t)N * HID * 2);  // [4][N][16] bf16
    float* bufA     = (float*)take((size_t)N * HID * 4);                // fp32 h
    float* ent_sum  = (float*)take((size_t)G * HID * 4);
    float* all_sum  = (float*)take((size_t)G * HID * 4);
    float* ent_cnt  = (float*)take((size_t)G * 4);
    float* node_cnt = (float*)take((size_t)G * 4);

    // pairs (E*4 B) aliases bufS (N*HID*2 B, same size) — free until k_gemm layer 1
    unsigned int* pairs = (unsigned int*)bufS;

    int nbkt = (N + BKT_W - 1) >> BKT_SHIFT;

    // ---- CSR build (bucketed) ----
    hipMemsetAsync(bkt_cnt, 0, (size_t)nbkt * 4, stream);
    k_bhist<<<(E + EPH - 1) / EPH, 256, 0, stream>>>(col, bkt_cnt, E, nbkt);
    k_bscan<<<1, 1, 0, stream>>>(bkt_cnt, bkt_base, nbkt);
    k_bcinit<<<(nbkt + 255) / 256, 256, 0, stream>>>(bkt_base, bcursor, nbkt);
    k_binA<<<(E + EPB - 1) / EPB, 256, 0, stream>>>(row, col, bcursor, pairs, E, nbkt);
    k_binB<<<nbkt, 256, 0, stream>>>(pairs, bkt_base, rowptr, srcs, dinv, N, E);

    // ---- layer 1 ----
    k_gemm<<<(N + 63) / 64, 256, 0, stream>>>(x, W1, dinv, bufS, N, K);
    for (int p = 0; p < 4; ++p)
        k_agg<<<(N + 3) / 4, 256, 0, stream>>>(bufS + (size_t)p * N * 16, rowptr, srcs,
                                               dinv, b1 + p * 16, bufA + p * 16, N);
    // ---- layer 2 ----
    k_gemm<<<(N + 63) / 64, 256, 0, stream>>>(bufA, W2, dinv, bufS, N, HID);
    for (int p = 0; p < 4; ++p)
        k_agg<<<(N + 3) / 4, 256, 0, stream>>>(bufS + (size_t)p * N * 16, rowptr, srcs,
                                               dinv, b2 + p * 16, bufA + p * 16, N);

    // ---- pooling ----
    hipMemsetAsync(ent_sum, 0, ((size_t)2 * G * HID + 2 * G) * 4, stream);
    k_pool<<<(N + PCHUNK * 4 - 1) / (PCHUNK * 4), 256, 0, stream>>>(
        bufA, batch, num_entity, ent_sum, all_sum, ent_cnt, node_cnt, N);

    // ---- head ----
    k_final<<<G, HID, 0, stream>>>(ent_sum, all_sum, ent_cnt, node_cnt, Wlin, blin, out, NCLS);
}

// Round 11
// 431.816 us; speedup vs baseline: 1.8051x; 1.8051x over previous
//
#include <hip/hip_runtime.h>
#include <math.h>

#define HID 64
#define BKT_W 256
#define BKT_SHIFT 8
#define MAX_BKT 512        // supports N <= 131072
#define EPB 4096
#define EPH 16384

__device__ __forceinline__ unsigned short f2bf(float x) {
    unsigned int b = __float_as_uint(x);
    unsigned int r = (b + 0x7FFFu + ((b >> 16) & 1u)) >> 16;   // RNE
    return (unsigned short)r;
}
__device__ __forceinline__ float bf2f(unsigned short u) {
    return __uint_as_float((unsigned int)u << 16);
}

// ---------------- bucket-level histogram ----------------
__global__ __launch_bounds__(256) void k_bhist(const int* __restrict__ col,
                                               int* __restrict__ bkt_cnt, int E, int nbkt) {
    __shared__ int h[MAX_BKT];
    int t = threadIdx.x;
    for (int b = t; b < nbkt; b += 256) h[b] = 0;
    __syncthreads();
    int e0 = blockIdx.x * EPH;
    int e1 = min(e0 + EPH, E);
    for (int e = e0 + t; e < e1; e += 256)
        atomicAdd(&h[col[e] >> BKT_SHIFT], 1);
    __syncthreads();
    for (int b = t; b < nbkt; b += 256)
        if (h[b]) atomicAdd(&bkt_cnt[b], h[b]);
}

__global__ void k_bscan(const int* __restrict__ bkt_cnt, int* __restrict__ bkt_base, int nbkt) {
    int run = 0;
    for (int b = 0; b < nbkt; ++b) { bkt_base[b] = run; run += bkt_cnt[b]; }
    bkt_base[nbkt] = run;
}

__global__ void k_bcinit(const int* __restrict__ bkt_base, int* __restrict__ bcursor, int nbkt) {
    int b = blockIdx.x * blockDim.x + threadIdx.x;
    if (b < nbkt) bcursor[b] = bkt_base[b];
}

// pass A: bin edges into bucket-contiguous packed (row<<8 | col&255) words
__global__ __launch_bounds__(256) void k_binA(const int* __restrict__ row,
                                              const int* __restrict__ col,
                                              int* __restrict__ bcursor,
                                              unsigned int* __restrict__ pairs,
                                              int E, int nbkt) {
    __shared__ int hist[MAX_BKT];
    __shared__ int base[MAX_BKT];
    int t = threadIdx.x;
    for (int b = t; b < nbkt; b += 256) hist[b] = 0;
    __syncthreads();
    int e0 = blockIdx.x * EPB;
    int myc[16], myr[16], myoff[16];
    #pragma unroll
    for (int i = 0; i < 16; ++i) {
        int e = e0 + t + i * 256;
        if (e < E) {
            myc[i] = col[e];
            myr[i] = row[e];
            myoff[i] = atomicAdd(&hist[myc[i] >> BKT_SHIFT], 1);
        }
    }
    __syncthreads();
    for (int b = t; b < nbkt; b += 256) {
        int h = hist[b];
        base[b] = h ? atomicAdd(&bcursor[b], h) : 0;
    }
    __syncthreads();
    #pragma unroll
    for (int i = 0; i < 16; ++i) {
        int e = e0 + t + i * 256;
        if (e < E) {
            int bk = myc[i] >> BKT_SHIFT;
            pairs[base[bk] + myoff[i]] =
                ((unsigned int)myr[i] << BKT_SHIFT) | (unsigned int)(myc[i] & (BKT_W - 1));
        }
    }
}

// pass B: per bucket — per-node counts in LDS, scan -> rowptr + dinv, scatter srcs
__global__ __launch_bounds__(256) void k_binB(const unsigned int* __restrict__ pairs,
                                              const int* __restrict__ bkt_base,
                                              int* __restrict__ rowptr,
                                              int* __restrict__ srcs,
                                              float* __restrict__ dinv,
                                              int n, int E) {
    __shared__ int cnt[BKT_W];
    __shared__ int s[BKT_W];
    __shared__ int lcur[BKT_W];
    int b = blockIdx.x, t = threadIdx.x;
    int n0 = b << BKT_SHIFT;
    int n1 = min(n0 + BKT_W, n);
    int s0 = bkt_base[b], s1 = bkt_base[b + 1];
    cnt[t] = 0;
    __syncthreads();
    for (int i = s0 + t; i < s1; i += 256)
        atomicAdd(&cnt[pairs[i] & (BKT_W - 1)], 1);
    __syncthreads();
    int v = cnt[t];
    s[t] = v;
    __syncthreads();
    #pragma unroll
    for (int off = 1; off < BKT_W; off <<= 1) {
        int tv = (t >= off) ? s[t - off] : 0;
        __syncthreads();
        s[t] += tv;
        __syncthreads();
    }
    int ex = s[t] - v;
    if (t < n1 - n0) {
        rowptr[n0 + t] = s0 + ex;
        dinv[n0 + t] = rsqrtf((float)(v + 1));   // +1 self-loop
    }
    lcur[t] = s0 + ex;
    __syncthreads();
    for (int i = s0 + t; i < s1; i += 256) {
        unsigned int p = pairs[i];
        int pos = atomicAdd(&lcur[p & (BKT_W - 1)], 1);
        srcs[pos] = (int)(p >> BKT_SHIFT);
    }
    if (n1 == n && t == 0) rowptr[n] = E;
}

// ---------------- GEMM: outS[i][c] = bf16( dinv[i] * (A@W)[i][c] ) ----------------
// 128x64 tile, 256 threads, 4x8 register blocking. sA stride 130 -> 2-way max conflicts.
#define SAP 130
__global__ __launch_bounds__(256) void k_gemm(const float* __restrict__ A,
                                              const float* __restrict__ W,
                                              const float* __restrict__ dinv,
                                              unsigned short* __restrict__ outS,
                                              int n, int K) {
    __shared__ float sA[32 * SAP];      // [kk][node] transposed, padded
    __shared__ float sW[32 * 64];       // [kk][col]
    int t = threadIdx.x;
    int m0 = blockIdx.x * 128;
    int tm = t >> 3, tn = t & 7;        // tm 0..31, tn 0..7
    float acc[4][8] = {};

    int arow = t >> 1;                  // 0..127
    int half = t & 1;                   // k-half: 0 -> k0..k0+15, 1 -> k0+16..k0+31

    for (int k0 = 0; k0 < K; k0 += 32) {
        // stage A: thread loads 16 consecutive k for one node, writes transposed
        {
            int node = m0 + arow;
            int ks = k0 + half * 16;
            float val[16];
            if (node < n && ks + 15 < K) {
                const float4* p = (const float4*)(A + (size_t)node * K + ks);
                float4 v0 = p[0], v1 = p[1], v2 = p[2], v3 = p[3];
                val[0]=v0.x; val[1]=v0.y; val[2]=v0.z; val[3]=v0.w;
                val[4]=v1.x; val[5]=v1.y; val[6]=v1.z; val[7]=v1.w;
                val[8]=v2.x; val[9]=v2.y; val[10]=v2.z; val[11]=v2.w;
                val[12]=v3.x; val[13]=v3.y; val[14]=v3.z; val[15]=v3.w;
            } else {
                #pragma unroll
                for (int u = 0; u < 16; ++u) {
                    int k = ks + u;
                    val[u] = (node < n && k < K) ? A[(size_t)node * K + k] : 0.0f;
                }
            }
            #pragma unroll
            for (int u = 0; u < 16; ++u)
                sA[(half * 16 + u) * SAP + arow] = val[u];
        }
        // stage W: 512 float4s over 256 threads (2 each)
        #pragma unroll
        for (int q = 0; q < 2; ++q) {
            int f = t + q * 256;        // 0..511
            int wrow = f >> 4;          // 0..31
            int wq = f & 15;            // float4 index within row
            int k = k0 + wrow;
            float4 v = {0.f, 0.f, 0.f, 0.f};
            if (k < K) v = *(const float4*)(W + (size_t)k * HID + wq * 4);
            *(float4*)&sW[wrow * 64 + wq * 4] = v;
        }
        __syncthreads();
        #pragma unroll
        for (int kk = 0; kk < 32; ++kk) {
            const float2* pa = (const float2*)&sA[kk * SAP + tm * 4];
            float2 a01 = pa[0], a23 = pa[1];
            float4 w0 = *(const float4*)&sW[kk * 64 + tn * 8];
            float4 w1 = *(const float4*)&sW[kk * 64 + tn * 8 + 4];
            float av[4] = { a01.x, a01.y, a23.x, a23.y };
            #pragma unroll
            for (int i = 0; i < 4; ++i) {
                float a = av[i];
                acc[i][0] = fmaf(a, w0.x, acc[i][0]);
                acc[i][1] = fmaf(a, w0.y, acc[i][1]);
                acc[i][2] = fmaf(a, w0.z, acc[i][2]);
                acc[i][3] = fmaf(a, w0.w, acc[i][3]);
                acc[i][4] = fmaf(a, w1.x, acc[i][4]);
                acc[i][5] = fmaf(a, w1.y, acc[i][5]);
                acc[i][6] = fmaf(a, w1.z, acc[i][6]);
                acc[i][7] = fmaf(a, w1.w, acc[i][7]);
            }
        }
        __syncthreads();
    }
    #pragma unroll
    for (int i = 0; i < 4; ++i) {
        int node = m0 + tm * 4 + i;
        if (node < n) {
            float d = dinv[node];
            ushort4 o0, o1;
            o0.x = f2bf(acc[i][0] * d); o0.y = f2bf(acc[i][1] * d);
            o0.z = f2bf(acc[i][2] * d); o0.w = f2bf(acc[i][3] * d);
            o1.x = f2bf(acc[i][4] * d); o1.y = f2bf(acc[i][5] * d);
            o1.z = f2bf(acc[i][6] * d); o1.w = f2bf(acc[i][7] * d);
            *(ushort4*)(outS + (size_t)node * HID + tn * 8)     = o0;
            *(ushort4*)(outS + (size_t)node * HID + tn * 8 + 4) = o1;
        }
    }
}

// ---------------- gather aggregation ----------------
// wave = 1 node. lane = e2*32 + c2: 32 lanes x uint (2 bf16 ch) cover a 64-ch row,
// 2 edges per gather instruction, 8 edges in flight. shfl_xor(32) combines halves.
__global__ __launch_bounds__(256) void k_agg(const unsigned int* __restrict__ bp32,
                                             const int* __restrict__ rowptr,
                                             const int* __restrict__ srcs,
                                             const float* __restrict__ dinv,
                                             const float* __restrict__ bias,
                                             float* __restrict__ out, int n) {
    int node = blockIdx.x * 4 + (threadIdx.x >> 6);
    if (node >= n) return;
    int lane = threadIdx.x & 63;
    int e2 = lane >> 5, c2 = lane & 31;
    float alo = 0.f, ahi = 0.f;
    if (e2 == 0) {                                     // self-loop term
        unsigned int u = bp32[(size_t)node * 32 + c2];
        alo = bf2f((unsigned short)u);
        ahi = bf2f((unsigned short)(u >> 16));
    }
    int s = rowptr[node], e = rowptr[node + 1];
    int k = s + e2;
    for (; k + 6 < e; k += 8) {
        int r0 = srcs[k], r1 = srcs[k + 2], r2 = srcs[k + 4], r3 = srcs[k + 6];
        unsigned int u0 = bp32[(size_t)r0 * 32 + c2];
        unsigned int u1 = bp32[(size_t)r1 * 32 + c2];
        unsigned int u2 = bp32[(size_t)r2 * 32 + c2];
        unsigned int u3 = bp32[(size_t)r3 * 32 + c2];
        alo += bf2f((unsigned short)u0) + bf2f((unsigned short)u1)
             + bf2f((unsigned short)u2) + bf2f((unsigned short)u3);
        ahi += bf2f((unsigned short)(u0 >> 16)) + bf2f((unsigned short)(u1 >> 16))
             + bf2f((unsigned short)(u2 >> 16)) + bf2f((unsigned short)(u3 >> 16));
    }
    for (; k < e; k += 2) {
        unsigned int u = bp32[(size_t)srcs[k] * 32 + c2];
        alo += bf2f((unsigned short)u);
        ahi += bf2f((unsigned short)(u >> 16));
    }
    alo += __shfl_xor(alo, 32);
    ahi += __shfl_xor(ahi, 32);
    if (lane < 32) {
        float d = dinv[node];
        float vlo = fmaf(alo, d, bias[2 * c2]);
        float vhi = fmaf(ahi, d, bias[2 * c2 + 1]);
        float2 o;
        o.x = vlo > 0.f ? vlo : 0.f;
        o.y = vhi > 0.f ? vhi : 0.f;
        *(float2*)(out + (size_t)node * HID + 2 * c2) = o;
    }
}

// ---------------- pooling ----------------
#define PCHUNK 128
__global__ void k_pool(const float* __restrict__ h, const int* __restrict__ batch,
                       const int* __restrict__ ne_arr,
                       float* ent_sum, float* all_sum, float* ent_cnt, float* node_cnt,
                       int n) {
    int wave = blockIdx.x * (blockDim.x >> 6) + (threadIdx.x >> 6);
    int j = threadIdx.x & 63;
    int i0 = wave * PCHUNK;
    if (i0 >= n) return;
    int iend = min(i0 + PCHUNK, n);
    int g = batch[i0];
    int ne = ne_arr[g];
    float ea = 0.f, aa = 0.f, ec = 0.f, nc = 0.f;
    for (int i = i0; i < iend; ++i) {
        int gi = batch[i];
        if (gi != g) {
            atomicAdd(&all_sum[g * HID + j], aa);
            atomicAdd(&ent_sum[g * HID + j], ea);
            if (j == 0) { atomicAdd(&node_cnt[g], nc); atomicAdd(&ent_cnt[g], ec); }
            g = gi; ne = ne_arr[g];
            ea = aa = ec = nc = 0.f;
        }
        float v = h[(size_t)i * HID + j];
        aa += v; nc += 1.f;
        if (i < ne) { ea += v; ec += 1.f; }
    }
    atomicAdd(&all_sum[g * HID + j], aa);
    atomicAdd(&ent_sum[g * HID + j], ea);
    if (j == 0) { atomicAdd(&node_cnt[g], nc); atomicAdd(&ent_cnt[g], ec); }
}

// ---------------- head ----------------
__global__ void k_final(const float* __restrict__ ent_sum, const float* __restrict__ all_sum,
                        const float* __restrict__ ent_cnt, const float* __restrict__ node_cnt,
                        const float* __restrict__ Wlin, const float* __restrict__ blin,
                        float* __restrict__ out, int ncls) {
    int g = blockIdx.x, j = threadIdx.x;
    __shared__ float pooled[HID];
    __shared__ float logits[32];
    float ec = ent_cnt[g];
    float p;
    if (ec > 0.0f)
        p = ent_sum[g * HID + j] / (ec + 1e-6f);
    else
        p = all_sum[g * HID + j] / node_cnt[g];
    pooled[j] = p;
    __syncthreads();
    if (j < ncls) {
        float acc = blin[j];
        for (int k = 0; k < HID; ++k)
            acc = fmaf(pooled[k], Wlin[k * ncls + j], acc);
        logits[j] = acc;
    }
    __syncthreads();
    if (j < ncls) {
        float m = -INFINITY;
        for (int c = 0; c < ncls; ++c) m = fmaxf(m, logits[c]);
        float s = 0.0f;
        for (int c = 0; c < ncls; ++c) s += expf(logits[c] - m);
        out[g * ncls + j] = logits[j] - m - logf(s);
    }
}

extern "C" void kernel_launch(void* const* d_in, const int* in_sizes, int n_in,
                              void* d_out, int out_size, void* d_ws, size_t ws_size,
                              hipStream_t stream) {
    const float* x          = (const float*)d_in[0];
    const int*   ei         = (const int*)d_in[1];
    const int*   batch      = (const int*)d_in[2];
    const int*   num_entity = (const int*)d_in[3];
    const float* W1         = (const float*)d_in[4];
    const float* b1         = (const float*)d_in[5];
    const float* W2         = (const float*)d_in[6];
    const float* b2         = (const float*)d_in[7];
    const float* Wlin       = (const float*)d_in[8];
    const float* blin       = (const float*)d_in[9];
    float* out = (float*)d_out;

    int N = in_sizes[2];
    int E = in_sizes[1] / 2;
    int K = in_sizes[0] / N;      // 300
    int G = in_sizes[3];
    int NCLS = in_sizes[9];

    const int* row = ei;          // source
    const int* col = ei + E;      // target

    // ---- workspace layout ----
    char* wsb = (char*)d_ws;
    size_t off = 0;
    auto take = [&](size_t bytes) -> void* {
        void* p = wsb + off;
        off += (bytes + 255) & ~(size_t)255;
        return p;
    };
    int*   rowptr   = (int*)take((size_t)(N + 1) * 4);
    float* dinv     = (float*)take((size_t)N * 4);
    int*   bkt_cnt  = (int*)take(MAX_BKT * 4);
    int*   bkt_base = (int*)take((MAX_BKT + 1) * 4);
    int*   bcursor  = (int*)take(MAX_BKT * 4);
    int*   srcs     = (int*)take((size_t)E * 4);
    unsigned short* bufS = (unsigned short*)take((size_t)N * HID * 2);  // [N][64] bf16
    float* bufA     = (float*)take((size_t)N * HID * 4);                // fp32 h
    float* ent_sum  = (float*)take((size_t)G * HID * 4);
    float* all_sum  = (float*)take((size_t)G * HID * 4);
    float* ent_cnt  = (float*)take((size_t)G * 4);
    float* node_cnt = (float*)take((size_t)G * 4);

    // pairs (E*4 B) aliases bufS (N*HID*2 B, same size) — free until layer-1 gemm
    unsigned int* pairs = (unsigned int*)bufS;

    int nbkt = (N + BKT_W - 1) >> BKT_SHIFT;

    // ---- CSR build (bucketed) ----
    hipMemsetAsync(bkt_cnt, 0, (size_t)nbkt * 4, stream);
    k_bhist<<<(E + EPH - 1) / EPH, 256, 0, stream>>>(col, bkt_cnt, E, nbkt);
    k_bscan<<<1, 1, 0, stream>>>(bkt_cnt, bkt_base, nbkt);
    k_bcinit<<<(nbkt + 255) / 256, 256, 0, stream>>>(bkt_base, bcursor, nbkt);
    k_binA<<<(E + EPB - 1) / EPB, 256, 0, stream>>>(row, col, bcursor, pairs, E, nbkt);
    k_binB<<<nbkt, 256, 0, stream>>>(pairs, bkt_base, rowptr, srcs, dinv, N, E);

    // ---- layer 1 ----
    k_gemm<<<(N + 127) / 128, 256, 0, stream>>>(x, W1, dinv, bufS, N, K);
    k_agg<<<(N + 3) / 4, 256, 0, stream>>>((const unsigned int*)bufS, rowptr, srcs,
                                           dinv, b1, bufA, N);
    // ---- layer 2 ----
    k_gemm<<<(N + 127) / 128, 256, 0, stream>>>(bufA, W2, dinv, bufS, N, HID);
    k_agg<<<(N + 3) / 4, 256, 0, stream>>>((const unsigned int*)bufS, rowptr, srcs,
                                           dinv, b2, bufA, N);

    // ---- pooling ----
    hipMemsetAsync(ent_sum, 0, ((size_t)2 * G * HID + 2 * G) * 4, stream);
    k_pool<<<(N + PCHUNK * 4 - 1) / (PCHUNK * 4), 256, 0, stream>>>(
        bufA, batch, num_entity, ent_sum, all_sum, ent_cnt, node_cnt, N);

    // ---- head ----
    k_final<<<G, HID, 0, stream>>>(ent_sum, all_sum, ent_cnt, node_cnt, Wlin, blin, out, NCLS);
}

// Round 13
// 418.997 us; speedup vs baseline: 1.8603x; 1.0306x over previous
//
#include <hip/hip_runtime.h>
#include <math.h>

#define HID 64
#define BKT_W 256
#define BKT_SHIFT 8
#define MAX_BKT 512        // supports N <= 131072
#define EPB 4096
#define EPH 16384

__device__ __forceinline__ unsigned short f2bf(float x) {
    unsigned int b = __float_as_uint(x);
    unsigned int r = (b + 0x7FFFu + ((b >> 16) & 1u)) >> 16;   // RNE
    return (unsigned short)r;
}
__device__ __forceinline__ float bf2f(unsigned short u) {
    return __uint_as_float((unsigned int)u << 16);
}

// ---------------- bucket-level histogram ----------------
__global__ __launch_bounds__(256) void k_bhist(const int* __restrict__ col,
                                               int* __restrict__ bkt_cnt, int E, int nbkt) {
    __shared__ int h[MAX_BKT];
    int t = threadIdx.x;
    for (int b = t; b < nbkt; b += 256) h[b] = 0;
    __syncthreads();
    int e0 = blockIdx.x * EPH;
    int e1 = min(e0 + EPH, E);
    for (int e = e0 + t; e < e1; e += 256)
        atomicAdd(&h[col[e] >> BKT_SHIFT], 1);
    __syncthreads();
    for (int b = t; b < nbkt; b += 256)
        if (h[b]) atomicAdd(&bkt_cnt[b], h[b]);
}

// scan over buckets + cursor init (single thread; nbkt ~ 391)
__global__ void k_bscan(const int* __restrict__ bkt_cnt, int* __restrict__ bkt_base,
                        int* __restrict__ bcursor, int nbkt) {
    int run = 0;
    for (int b = 0; b < nbkt; ++b) {
        bkt_base[b] = run;
        bcursor[b] = run;
        run += bkt_cnt[b];
    }
    bkt_base[nbkt] = run;
}

// pass A: bin edges into bucket-contiguous packed (row<<8 | col&255) words
__global__ __launch_bounds__(256) void k_binA(const int* __restrict__ row,
                                              const int* __restrict__ col,
                                              int* __restrict__ bcursor,
                                              unsigned int* __restrict__ pairs,
                                              int E, int nbkt) {
    __shared__ int hist[MAX_BKT];
    __shared__ int base[MAX_BKT];
    int t = threadIdx.x;
    for (int b = t; b < nbkt; b += 256) hist[b] = 0;
    __syncthreads();
    int e0 = blockIdx.x * EPB;
    int myc[16], myr[16], myoff[16];
    #pragma unroll
    for (int i = 0; i < 16; ++i) {
        int e = e0 + t + i * 256;
        if (e < E) {
            myc[i] = col[e];
            myr[i] = row[e];
            myoff[i] = atomicAdd(&hist[myc[i] >> BKT_SHIFT], 1);
        }
    }
    __syncthreads();
    for (int b = t; b < nbkt; b += 256) {
        int h = hist[b];
        base[b] = h ? atomicAdd(&bcursor[b], h) : 0;
    }
    __syncthreads();
    #pragma unroll
    for (int i = 0; i < 16; ++i) {
        int e = e0 + t + i * 256;
        if (e < E) {
            int bk = myc[i] >> BKT_SHIFT;
            pairs[base[bk] + myoff[i]] =
                ((unsigned int)myr[i] << BKT_SHIFT) | (unsigned int)(myc[i] & (BKT_W - 1));
        }
    }
}

// pass B: per bucket — per-node counts in LDS, scan -> rowptr + dinv, scatter srcs
__global__ __launch_bounds__(256) void k_binB(const unsigned int* __restrict__ pairs,
                                              const int* __restrict__ bkt_base,
                                              int* __restrict__ rowptr,
                                              int* __restrict__ srcs,
                                              float* __restrict__ dinv,
                                              int n, int E) {
    __shared__ int cnt[BKT_W];
    __shared__ int s[BKT_W];
    __shared__ int lcur[BKT_W];
    int b = blockIdx.x, t = threadIdx.x;
    int n0 = b << BKT_SHIFT;
    int n1 = min(n0 + BKT_W, n);
    int s0 = bkt_base[b], s1 = bkt_base[b + 1];
    cnt[t] = 0;
    __syncthreads();
    for (int i = s0 + t; i < s1; i += 256)
        atomicAdd(&cnt[pairs[i] & (BKT_W - 1)], 1);
    __syncthreads();
    int v = cnt[t];
    s[t] = v;
    __syncthreads();
    #pragma unroll
    for (int off = 1; off < BKT_W; off <<= 1) {
        int tv = (t >= off) ? s[t - off] : 0;
        __syncthreads();
        s[t] += tv;
        __syncthreads();
    }
    int ex = s[t] - v;
    if (t < n1 - n0) {
        rowptr[n0 + t] = s0 + ex;
        dinv[n0 + t] = rsqrtf((float)(v + 1));   // +1 self-loop
    }
    lcur[t] = s0 + ex;
    __syncthreads();
    for (int i = s0 + t; i < s1; i += 256) {
        unsigned int p = pairs[i];
        int pos = atomicAdd(&lcur[p & (BKT_W - 1)], 1);
        srcs[pos] = (int)(p >> BKT_SHIFT);
    }
    if (n1 == n && t == 0) rowptr[n] = E;
}

// ---------------- GEMM: outS[i][c] = bf16( dinv[i] * (A@W)[i][c] ) ----------------
// 64x64 tile, 256 threads, 4x4 micro-tile, K-chunk 32. Stride-68 padding keeps
// float4 LDS ops 16B-aligned while breaking the stride-64 bank pathology.
#define SAP 68
__global__ __launch_bounds__(256) void k_gemm(const float* __restrict__ A,
                                              const float* __restrict__ W,
                                              const float* __restrict__ dinv,
                                              unsigned short* __restrict__ outS,
                                              int n, int K) {
    __shared__ float sA[32 * SAP];      // [kk][m] transposed
    __shared__ float sW[32 * SAP];      // [kk][c]
    int t = threadIdx.x;
    int m0 = blockIdx.x * 64;
    int tm = t >> 4, tn = t & 15;       // 16x16 threads -> 4 rows x 4 cols each
    float acc[4][4] = {};

    int arow = t >> 2;                  // 0..63
    int akb  = (t & 3) * 8;             // 0,8,16,24

    for (int k0 = 0; k0 < K; k0 += 32) {
        // stage A (transposed)
        {
            int node = m0 + arow;
            if (node < n && k0 + akb + 7 < K) {
                const float4* p = (const float4*)(A + (size_t)node * K + k0 + akb);
                float4 v0 = p[0], v1 = p[1];
                float val[8] = {v0.x, v0.y, v0.z, v0.w, v1.x, v1.y, v1.z, v1.w};
                #pragma unroll
                for (int u = 0; u < 8; ++u)
                    sA[(akb + u) * SAP + arow] = val[u];
            } else {
                #pragma unroll
                for (int u = 0; u < 8; ++u) {
                    int k = k0 + akb + u;
                    sA[(akb + u) * SAP + arow] = (node < n && k < K) ? A[(size_t)node * K + k] : 0.0f;
                }
            }
        }
        // stage W: 32 rows x 16 float4 = 512 over 256 threads (2 each)
        #pragma unroll
        for (int q = 0; q < 2; ++q) {
            int idx = t + q * 256;      // 0..511
            int wr = idx >> 4;          // 0..31
            int wc4 = idx & 15;         // float4 index
            int k = k0 + wr;
            float4 v = {0.f, 0.f, 0.f, 0.f};
            if (k < K) v = *(const float4*)(W + (size_t)k * HID + wc4 * 4);
            *(float4*)&sW[wr * SAP + wc4 * 4] = v;
        }
        __syncthreads();
        #pragma unroll
        for (int kk = 0; kk < 32; ++kk) {
            float4 av = *(const float4*)&sA[kk * SAP + tm * 4];
            float4 wv = *(const float4*)&sW[kk * SAP + tn * 4];
            const float* ap = &av.x;
            #pragma unroll
            for (int i = 0; i < 4; ++i) {
                float a = ap[i];
                acc[i][0] = fmaf(a, wv.x, acc[i][0]);
                acc[i][1] = fmaf(a, wv.y, acc[i][1]);
                acc[i][2] = fmaf(a, wv.z, acc[i][2]);
                acc[i][3] = fmaf(a, wv.w, acc[i][3]);
            }
        }
        __syncthreads();
    }
    #pragma unroll
    for (int i = 0; i < 4; ++i) {
        int node = m0 + tm * 4 + i;
        if (node < n) {
            float d = dinv[node];
            ushort4 o;
            o.x = f2bf(acc[i][0] * d);
            o.y = f2bf(acc[i][1] * d);
            o.z = f2bf(acc[i][2] * d);
            o.w = f2bf(acc[i][3] * d);
            *(ushort4*)(outS + (size_t)node * HID + tn * 4) = o;
        }
    }
}

// ---------------- gather aggregation ----------------
// wave = 1 node. lane = e4*16 + c4: 16 lanes x uint2 (4 bf16 ch) cover the 64-ch row,
// 4 edges per gather instruction, 8 edges in flight. shfl_xor(16,32) combines.
__global__ __launch_bounds__(256) void k_agg(const uint2* __restrict__ bp,
                                             const int* __restrict__ rowptr,
                                             const int* __restrict__ srcs,
                                             const float* __restrict__ dinv,
                                             const float* __restrict__ bias,
                                             float* __restrict__ out, int n) {
    int node = blockIdx.x * 4 + (threadIdx.x >> 6);
    if (node >= n) return;
    int lane = threadIdx.x & 63;
    int e4 = lane >> 4, c4 = lane & 15;
    float a0 = 0.f, a1 = 0.f, a2 = 0.f, a3 = 0.f;
    if (e4 == 0) {                                     // self-loop term
        uint2 u = bp[(size_t)node * 16 + c4];
        a0 = bf2f((unsigned short)u.x);
        a1 = bf2f((unsigned short)(u.x >> 16));
        a2 = bf2f((unsigned short)u.y);
        a3 = bf2f((unsigned short)(u.y >> 16));
    }
    int s = rowptr[node], e = rowptr[node + 1];
    int k = s + e4;
    for (; k + 4 < e; k += 8) {
        int r0 = srcs[k];
        int r1 = srcs[k + 4];
        uint2 ua = bp[(size_t)r0 * 16 + c4];
        uint2 ub = bp[(size_t)r1 * 16 + c4];
        a0 += bf2f((unsigned short)ua.x) + bf2f((unsigned short)ub.x);
        a1 += bf2f((unsigned short)(ua.x >> 16)) + bf2f((unsigned short)(ub.x >> 16));
        a2 += bf2f((unsigned short)ua.y) + bf2f((unsigned short)ub.y);
        a3 += bf2f((unsigned short)(ua.y >> 16)) + bf2f((unsigned short)(ub.y >> 16));
    }
    if (k < e) {
        uint2 u = bp[(size_t)srcs[k] * 16 + c4];
        a0 += bf2f((unsigned short)u.x);
        a1 += bf2f((unsigned short)(u.x >> 16));
        a2 += bf2f((unsigned short)u.y);
        a3 += bf2f((unsigned short)(u.y >> 16));
    }
    a0 += __shfl_xor(a0, 16); a0 += __shfl_xor(a0, 32);
    a1 += __shfl_xor(a1, 16); a1 += __shfl_xor(a1, 32);
    a2 += __shfl_xor(a2, 16); a2 += __shfl_xor(a2, 32);
    a3 += __shfl_xor(a3, 16); a3 += __shfl_xor(a3, 32);
    if (lane < 16) {
        float d = dinv[node];
        float4 bs = *(const float4*)(bias + c4 * 4);
        float4 o;
        o.x = fmaf(a0, d, bs.x); o.x = o.x > 0.f ? o.x : 0.f;
        o.y = fmaf(a1, d, bs.y); o.y = o.y > 0.f ? o.y : 0.f;
        o.z = fmaf(a2, d, bs.z); o.z = o.z > 0.f ? o.z : 0.f;
        o.w = fmaf(a3, d, bs.w); o.w = o.w > 0.f ? o.w : 0.f;
        *(float4*)(out + (size_t)node * HID + c4 * 4) = o;
    }
}

// ---------------- pooling ----------------
#define PCHUNK 128
__global__ void k_pool(const float* __restrict__ h, const int* __restrict__ batch,
                       const int* __restrict__ ne_arr,
                       float* ent_sum, float* all_sum, float* ent_cnt, float* node_cnt,
                       int n) {
    int wave = blockIdx.x * (blockDim.x >> 6) + (threadIdx.x >> 6);
    int j = threadIdx.x & 63;
    int i0 = wave * PCHUNK;
    if (i0 >= n) return;
    int iend = min(i0 + PCHUNK, n);
    int g = batch[i0];
    int ne = ne_arr[g];
    float ea = 0.f, aa = 0.f, ec = 0.f, nc = 0.f;
    for (int i = i0; i < iend; ++i) {
        int gi = batch[i];
        if (gi != g) {
            atomicAdd(&all_sum[g * HID + j], aa);
            atomicAdd(&ent_sum[g * HID + j], ea);
            if (j == 0) { atomicAdd(&node_cnt[g], nc); atomicAdd(&ent_cnt[g], ec); }
            g = gi; ne = ne_arr[g];
            ea = aa = ec = nc = 0.f;
        }
        float v = h[(size_t)i * HID + j];
        aa += v; nc += 1.f;
        if (i < ne) { ea += v; ec += 1.f; }
    }
    atomicAdd(&all_sum[g * HID + j], aa);
    atomicAdd(&ent_sum[g * HID + j], ea);
    if (j == 0) { atomicAdd(&node_cnt[g], nc); atomicAdd(&ent_cnt[g], ec); }
}

// ---------------- head ----------------
__global__ void k_final(const float* __restrict__ ent_sum, const float* __restrict__ all_sum,
                        const float* __restrict__ ent_cnt, const float* __restrict__ node_cnt,
                        const float* __restrict__ Wlin, const float* __restrict__ blin,
                        float* __restrict__ out, int ncls) {
    int g = blockIdx.x, j = threadIdx.x;
    __shared__ float pooled[HID];
    __shared__ float logits[32];
    float ec = ent_cnt[g];
    float p;
    if (ec > 0.0f)
        p = ent_sum[g * HID + j] / (ec + 1e-6f);
    else
        p = all_sum[g * HID + j] / node_cnt[g];
    pooled[j] = p;
    __syncthreads();
    if (j < ncls) {
        float acc = blin[j];
        for (int k = 0; k < HID; ++k)
            acc = fmaf(pooled[k], Wlin[k * ncls + j], acc);
        logits[j] = acc;
    }
    __syncthreads();
    if (j < ncls) {
        float m = -INFINITY;
        for (int c = 0; c < ncls; ++c) m = fmaxf(m, logits[c]);
        float s = 0.0f;
        for (int c = 0; c < ncls; ++c) s += expf(logits[c] - m);
        out[g * ncls + j] = logits[j] - m - logf(s);
    }
}

extern "C" void kernel_launch(void* const* d_in, const int* in_sizes, int n_in,
                              void* d_out, int out_size, void* d_ws, size_t ws_size,
                              hipStream_t stream) {
    const float* x          = (const float*)d_in[0];
    const int*   ei         = (const int*)d_in[1];
    const int*   batch      = (const int*)d_in[2];
    const int*   num_entity = (const int*)d_in[3];
    const float* W1         = (const float*)d_in[4];
    const float* b1         = (const float*)d_in[5];
    const float* W2         = (const float*)d_in[6];
    const float* b2         = (const float*)d_in[7];
    const float* Wlin       = (const float*)d_in[8];
    const float* blin       = (const float*)d_in[9];
    float* out = (float*)d_out;

    int N = in_sizes[2];
    int E = in_sizes[1] / 2;
    int K = in_sizes[0] / N;      // 300
    int G = in_sizes[3];
    int NCLS = in_sizes[9];

    const int* row = ei;          // source
    const int* col = ei + E;      // target

    // ---- workspace layout ----
    char* wsb = (char*)d_ws;
    size_t off = 0;
    auto take = [&](size_t bytes) -> void* {
        void* p = wsb + off;
        off += (bytes + 255) & ~(size_t)255;
        return p;
    };
    int*   rowptr   = (int*)take((size_t)(N + 1) * 4);
    float* dinv     = (float*)take((size_t)N * 4);
    int*   bkt_cnt  = (int*)take(MAX_BKT * 4);
    int*   bkt_base = (int*)take((MAX_BKT + 1) * 4);
    int*   bcursor  = (int*)take(MAX_BKT * 4);
    int*   srcs     = (int*)take((size_t)E * 4);
    unsigned short* bufS = (unsigned short*)take((size_t)N * HID * 2);  // [N][64] bf16
    float* bufA     = (float*)take((size_t)N * HID * 4);                // fp32 h
    float* ent_sum  = (float*)take((size_t)G * HID * 4);
    float* all_sum  = (float*)take((size_t)G * HID * 4);
    float* ent_cnt  = (float*)take((size_t)G * 4);
    float* node_cnt = (float*)take((size_t)G * 4);

    // pairs (E*4 B) aliases bufS (N*HID*2 B, same size) — free until layer-1 gemm
    unsigned int* pairs = (unsigned int*)bufS;

    int nbkt = (N + BKT_W - 1) >> BKT_SHIFT;

    // ---- CSR build (bucketed) ----
    hipMemsetAsync(bkt_cnt, 0, (size_t)nbkt * 4, stream);
    k_bhist<<<(E + EPH - 1) / EPH, 256, 0, stream>>>(col, bkt_cnt, E, nbkt);
    k_bscan<<<1, 1, 0, stream>>>(bkt_cnt, bkt_base, bcursor, nbkt);
    k_binA<<<(E + EPB - 1) / EPB, 256, 0, stream>>>(row, col, bcursor, pairs, E, nbkt);
    k_binB<<<nbkt, 256, 0, stream>>>(pairs, bkt_base, rowptr, srcs, dinv, N, E);

    // ---- layer 1 ----
    k_gemm<<<(N + 63) / 64, 256, 0, stream>>>(x, W1, dinv, bufS, N, K);
    k_agg<<<(N + 3) / 4, 256, 0, stream>>>((const uint2*)bufS, rowptr, srcs,
                                           dinv, b1, bufA, N);
    // ---- layer 2 ----
    k_gemm<<<(N + 63) / 64, 256, 0, stream>>>(bufA, W2, dinv, bufS, N, HID);
    k_agg<<<(N + 3) / 4, 256, 0, stream>>>((const uint2*)bufS, rowptr, srcs,
                                           dinv, b2, bufA, N);

    // ---- pooling ----
    hipMemsetAsync(ent_sum, 0, ((size_t)2 * G * HID + 2 * G) * 4, stream);
    k_pool<<<(N + PCHUNK * 4 - 1) / (PCHUNK * 4), 256, 0, stream>>>(
        bufA, batch, num_entity, ent_sum, all_sum, ent_cnt, node_cnt, N);

    // ---- head ----
    k_final<<<G, HID, 0, stream>>>(ent_sum, all_sum, ent_cnt, node_cnt, Wlin, blin, out, NCLS);
}

// Round 14
// 416.931 us; speedup vs baseline: 1.8695x; 1.0050x over previous
//
#include <hip/hip_runtime.h>
#include <hip/hip_fp16.h>
#include <math.h>

#define HID 64
#define BKT_W 256
#define BKT_SHIFT 8
#define MAX_BKT 512        // supports N <= 131072
#define EPB 4096
#define EPH 16384

__device__ __forceinline__ unsigned int hadd2u(unsigned int a, unsigned int b) {
    __half2 r = __hadd2(*(__half2*)&a, *(__half2*)&b);
    return *(unsigned int*)&r;
}

// ---------------- bucket-level histogram ----------------
__global__ __launch_bounds__(256) void k_bhist(const int* __restrict__ col,
                                               int* __restrict__ bkt_cnt, int E, int nbkt) {
    __shared__ int h[MAX_BKT];
    int t = threadIdx.x;
    for (int b = t; b < nbkt; b += 256) h[b] = 0;
    __syncthreads();
    int e0 = blockIdx.x * EPH;
    int e1 = min(e0 + EPH, E);
    for (int e = e0 + t; e < e1; e += 256)
        atomicAdd(&h[col[e] >> BKT_SHIFT], 1);
    __syncthreads();
    for (int b = t; b < nbkt; b += 256)
        if (h[b]) atomicAdd(&bkt_cnt[b], h[b]);
}

// scan over buckets + cursor init (single thread; nbkt ~ 391)
__global__ void k_bscan(const int* __restrict__ bkt_cnt, int* __restrict__ bkt_base,
                        int* __restrict__ bcursor, int nbkt) {
    int run = 0;
    for (int b = 0; b < nbkt; ++b) {
        bkt_base[b] = run;
        bcursor[b] = run;
        run += bkt_cnt[b];
    }
    bkt_base[nbkt] = run;
}

// pass A: bin edges into bucket-contiguous packed (row<<8 | col&255) words
__global__ __launch_bounds__(256) void k_binA(const int* __restrict__ row,
                                              const int* __restrict__ col,
                                              int* __restrict__ bcursor,
                                              unsigned int* __restrict__ pairs,
                                              int E, int nbkt) {
    __shared__ int hist[MAX_BKT];
    __shared__ int base[MAX_BKT];
    int t = threadIdx.x;
    for (int b = t; b < nbkt; b += 256) hist[b] = 0;
    __syncthreads();
    int e0 = blockIdx.x * EPB;
    int myc[16], myr[16], myoff[16];
    #pragma unroll
    for (int i = 0; i < 16; ++i) {
        int e = e0 + t + i * 256;
        if (e < E) {
            myc[i] = col[e];
            myr[i] = row[e];
            myoff[i] = atomicAdd(&hist[myc[i] >> BKT_SHIFT], 1);
        }
    }
    __syncthreads();
    for (int b = t; b < nbkt; b += 256) {
        int h = hist[b];
        base[b] = h ? atomicAdd(&bcursor[b], h) : 0;
    }
    __syncthreads();
    #pragma unroll
    for (int i = 0; i < 16; ++i) {
        int e = e0 + t + i * 256;
        if (e < E) {
            int bk = myc[i] >> BKT_SHIFT;
            pairs[base[bk] + myoff[i]] =
                ((unsigned int)myr[i] << BKT_SHIFT) | (unsigned int)(myc[i] & (BKT_W - 1));
        }
    }
}

// pass B: per bucket — per-node counts in LDS, scan -> rowptr + dinv, scatter srcs
__global__ __launch_bounds__(256) void k_binB(const unsigned int* __restrict__ pairs,
                                              const int* __restrict__ bkt_base,
                                              int* __restrict__ rowptr,
                                              int* __restrict__ srcs,
                                              float* __restrict__ dinv,
                                              int n, int E) {
    __shared__ int cnt[BKT_W];
    __shared__ int s[BKT_W];
    __shared__ int lcur[BKT_W];
    int b = blockIdx.x, t = threadIdx.x;
    int n0 = b << BKT_SHIFT;
    int n1 = min(n0 + BKT_W, n);
    int s0 = bkt_base[b], s1 = bkt_base[b + 1];
    cnt[t] = 0;
    __syncthreads();
    for (int i = s0 + t; i < s1; i += 256)
        atomicAdd(&cnt[pairs[i] & (BKT_W - 1)], 1);
    __syncthreads();
    int v = cnt[t];
    s[t] = v;
    __syncthreads();
    #pragma unroll
    for (int off = 1; off < BKT_W; off <<= 1) {
        int tv = (t >= off) ? s[t - off] : 0;
        __syncthreads();
        s[t] += tv;
        __syncthreads();
    }
    int ex = s[t] - v;
    if (t < n1 - n0) {
        rowptr[n0 + t] = s0 + ex;
        dinv[n0 + t] = rsqrtf((float)(v + 1));   // +1 self-loop
    }
    lcur[t] = s0 + ex;
    __syncthreads();
    for (int i = s0 + t; i < s1; i += 256) {
        unsigned int p = pairs[i];
        int pos = atomicAdd(&lcur[p & (BKT_W - 1)], 1);
        srcs[pos] = (int)(p >> BKT_SHIFT);
    }
    if (n1 == n && t == 0) rowptr[n] = E;
}

// ---------------- GEMM: outH[i][c] = fp16( dinv[i] * (A@W)[i][c] ) ----------------
// 64x64 tile, BK=64, 256 threads, 4x4 micro-tile.
// sA stride 65 (== 1 mod 32): staging writes exactly 2 lanes/bank (free);
// compute reads are 16-lane broadcasts (conflict-free). sW stride 68, float4-aligned.
#define SAPA 65
#define SAPW 68
__global__ __launch_bounds__(256) void k_gemm(const float* __restrict__ A,
                                              const float* __restrict__ W,
                                              const float* __restrict__ dinv,
                                              unsigned short* __restrict__ outH,
                                              int n, int K) {
    __shared__ float sA[64 * SAPA];     // [kk][m] transposed
    __shared__ float sW[64 * SAPW];     // [kk][c]
    int t = threadIdx.x;
    int m0 = blockIdx.x * 64;
    int tm = t >> 4, tn = t & 15;       // 4 rows x 4 cols per thread
    float acc[4][4] = {};

    int arow = t >> 2;                  // 0..63
    int akq  = (t & 3) * 16;            // k sub-range base: 0,16,32,48

    for (int k0 = 0; k0 < K; k0 += 64) {
        // stage A: thread loads 16 consecutive k (4 float4) for one node
        {
            int node = m0 + arow;
            #pragma unroll
            for (int u = 0; u < 4; ++u) {
                int ks = k0 + akq + u * 4;
                float4 v = {0.f, 0.f, 0.f, 0.f};
                if (node < n) {
                    if (ks + 3 < K) {
                        v = *(const float4*)(A + (size_t)node * K + ks);
                    } else {
                        float tmp[4] = {0.f, 0.f, 0.f, 0.f};
                        for (int w = 0; w < 4; ++w)
                            if (ks + w < K) tmp[w] = A[(size_t)node * K + ks + w];
                        v = {tmp[0], tmp[1], tmp[2], tmp[3]};
                    }
                }
                sA[(akq + u * 4 + 0) * SAPA + arow] = v.x;
                sA[(akq + u * 4 + 1) * SAPA + arow] = v.y;
                sA[(akq + u * 4 + 2) * SAPA + arow] = v.z;
                sA[(akq + u * 4 + 3) * SAPA + arow] = v.w;
            }
        }
        // stage W: 64 rows x 16 float4 = 1024 over 256 threads (4 each)
        #pragma unroll
        for (int q = 0; q < 4; ++q) {
            int idx = t + q * 256;      // 0..1023
            int wr = idx >> 4;          // 0..63
            int wc4 = idx & 15;
            int k = k0 + wr;
            float4 v = {0.f, 0.f, 0.f, 0.f};
            if (k < K) v = *(const float4*)(W + (size_t)k * HID + wc4 * 4);
            *(float4*)&sW[wr * SAPW + wc4 * 4] = v;
        }
        __syncthreads();
        #pragma unroll
        for (int kk = 0; kk < 64; ++kk) {
            float a0v = sA[kk * SAPA + tm * 4 + 0];
            float a1v = sA[kk * SAPA + tm * 4 + 1];
            float a2v = sA[kk * SAPA + tm * 4 + 2];
            float a3v = sA[kk * SAPA + tm * 4 + 3];
            float4 wv = *(const float4*)&sW[kk * SAPW + tn * 4];
            acc[0][0] = fmaf(a0v, wv.x, acc[0][0]);
            acc[0][1] = fmaf(a0v, wv.y, acc[0][1]);
            acc[0][2] = fmaf(a0v, wv.z, acc[0][2]);
            acc[0][3] = fmaf(a0v, wv.w, acc[0][3]);
            acc[1][0] = fmaf(a1v, wv.x, acc[1][0]);
            acc[1][1] = fmaf(a1v, wv.y, acc[1][1]);
            acc[1][2] = fmaf(a1v, wv.z, acc[1][2]);
            acc[1][3] = fmaf(a1v, wv.w, acc[1][3]);
            acc[2][0] = fmaf(a2v, wv.x, acc[2][0]);
            acc[2][1] = fmaf(a2v, wv.y, acc[2][1]);
            acc[2][2] = fmaf(a2v, wv.z, acc[2][2]);
            acc[2][3] = fmaf(a2v, wv.w, acc[2][3]);
            acc[3][0] = fmaf(a3v, wv.x, acc[3][0]);
            acc[3][1] = fmaf(a3v, wv.y, acc[3][1]);
            acc[3][2] = fmaf(a3v, wv.z, acc[3][2]);
            acc[3][3] = fmaf(a3v, wv.w, acc[3][3]);
        }
        __syncthreads();
    }
    #pragma unroll
    for (int i = 0; i < 4; ++i) {
        int node = m0 + tm * 4 + i;
        if (node < n) {
            float d = dinv[node];
            float2 lo = {acc[i][0] * d, acc[i][1] * d};
            float2 hi = {acc[i][2] * d, acc[i][3] * d};
            __half2 h01 = __float22half2_rn(lo);
            __half2 h23 = __float22half2_rn(hi);
            uint2 o;
            o.x = *(unsigned int*)&h01;
            o.y = *(unsigned int*)&h23;
            *(uint2*)(outH + (size_t)node * HID + tn * 4) = o;
        }
    }
}

// ---------------- gather aggregation (fp16 messages, packed adds) ----------------
// wave = 1 node. lane = e4*16 + c4: 16 lanes x uint2 (4 fp16 ch) cover the 64-ch row,
// 4 edges per gather instruction, 8 edges in flight. v_pk_add_f16 accumulate.
__global__ __launch_bounds__(256) void k_agg(const uint2* __restrict__ bp,
                                             const int* __restrict__ rowptr,
                                             const int* __restrict__ srcs,
                                             const float* __restrict__ dinv,
                                             const float* __restrict__ bias,
                                             float* __restrict__ out, int n) {
    int node = blockIdx.x * 4 + (threadIdx.x >> 6);
    if (node >= n) return;
    int lane = threadIdx.x & 63;
    int e4 = lane >> 4, c4 = lane & 15;
    unsigned int a01 = 0u, a23 = 0u;                   // half2 zeros
    if (e4 == 0) {                                     // self-loop term
        uint2 u = bp[(size_t)node * 16 + c4];
        a01 = u.x; a23 = u.y;
    }
    int s = rowptr[node], e = rowptr[node + 1];
    int k = s + e4;
    for (; k + 4 < e; k += 8) {
        int r0 = srcs[k];
        int r1 = srcs[k + 4];
        uint2 ua = bp[(size_t)r0 * 16 + c4];
        uint2 ub = bp[(size_t)r1 * 16 + c4];
        a01 = hadd2u(a01, ua.x);
        a23 = hadd2u(a23, ua.y);
        a01 = hadd2u(a01, ub.x);
        a23 = hadd2u(a23, ub.y);
    }
    if (k < e) {
        uint2 u = bp[(size_t)srcs[k] * 16 + c4];
        a01 = hadd2u(a01, u.x);
        a23 = hadd2u(a23, u.y);
    }
    a01 = hadd2u(a01, (unsigned int)__shfl_xor((int)a01, 16));
    a01 = hadd2u(a01, (unsigned int)__shfl_xor((int)a01, 32));
    a23 = hadd2u(a23, (unsigned int)__shfl_xor((int)a23, 16));
    a23 = hadd2u(a23, (unsigned int)__shfl_xor((int)a23, 32));
    if (lane < 16) {
        float d = dinv[node];
        float2 f01 = __half22float2(*(__half2*)&a01);
        float2 f23 = __half22float2(*(__half2*)&a23);
        float4 bs = *(const float4*)(bias + c4 * 4);
        float4 o;
        o.x = fmaf(f01.x, d, bs.x); o.x = o.x > 0.f ? o.x : 0.f;
        o.y = fmaf(f01.y, d, bs.y); o.y = o.y > 0.f ? o.y : 0.f;
        o.z = fmaf(f23.x, d, bs.z); o.z = o.z > 0.f ? o.z : 0.f;
        o.w = fmaf(f23.y, d, bs.w); o.w = o.w > 0.f ? o.w : 0.f;
        *(float4*)(out + (size_t)node * HID + c4 * 4) = o;
    }
}

// ---------------- pooling ----------------
#define PCHUNK 128
__global__ void k_pool(const float* __restrict__ h, const int* __restrict__ batch,
                       const int* __restrict__ ne_arr,
                       float* ent_sum, float* all_sum, float* ent_cnt, float* node_cnt,
                       int n) {
    int wave = blockIdx.x * (blockDim.x >> 6) + (threadIdx.x >> 6);
    int j = threadIdx.x & 63;
    int i0 = wave * PCHUNK;
    if (i0 >= n) return;
    int iend = min(i0 + PCHUNK, n);
    int g = batch[i0];
    int ne = ne_arr[g];
    float ea = 0.f, aa = 0.f, ec = 0.f, nc = 0.f;
    for (int i = i0; i < iend; ++i) {
        int gi = batch[i];
        if (gi != g) {
            atomicAdd(&all_sum[g * HID + j], aa);
            atomicAdd(&ent_sum[g * HID + j], ea);
            if (j == 0) { atomicAdd(&node_cnt[g], nc); atomicAdd(&ent_cnt[g], ec); }
            g = gi; ne = ne_arr[g];
            ea = aa = ec = nc = 0.f;
        }
        float v = h[(size_t)i * HID + j];
        aa += v; nc += 1.f;
        if (i < ne) { ea += v; ec += 1.f; }
    }
    atomicAdd(&all_sum[g * HID + j], aa);
    atomicAdd(&ent_sum[g * HID + j], ea);
    if (j == 0) { atomicAdd(&node_cnt[g], nc); atomicAdd(&ent_cnt[g], ec); }
}

// ---------------- head ----------------
__global__ void k_final(const float* __restrict__ ent_sum, const float* __restrict__ all_sum,
                        const float* __restrict__ ent_cnt, const float* __restrict__ node_cnt,
                        const float* __restrict__ Wlin, const float* __restrict__ blin,
                        float* __restrict__ out, int ncls) {
    int g = blockIdx.x, j = threadIdx.x;
    __shared__ float pooled[HID];
    __shared__ float logits[32];
    float ec = ent_cnt[g];
    float p;
    if (ec > 0.0f)
        p = ent_sum[g * HID + j] / (ec + 1e-6f);
    else
        p = all_sum[g * HID + j] / node_cnt[g];
    pooled[j] = p;
    __syncthreads();
    if (j < ncls) {
        float acc = blin[j];
        for (int k = 0; k < HID; ++k)
            acc = fmaf(pooled[k], Wlin[k * ncls + j], acc);
        logits[j] = acc;
    }
    __syncthreads();
    if (j < ncls) {
        float m = -INFINITY;
        for (int c = 0; c < ncls; ++c) m = fmaxf(m, logits[c]);
        float s = 0.0f;
        for (int c = 0; c < ncls; ++c) s += expf(logits[c] - m);
        out[g * ncls + j] = logits[j] - m - logf(s);
    }
}

extern "C" void kernel_launch(void* const* d_in, const int* in_sizes, int n_in,
                              void* d_out, int out_size, void* d_ws, size_t ws_size,
                              hipStream_t stream) {
    const float* x          = (const float*)d_in[0];
    const int*   ei         = (const int*)d_in[1];
    const int*   batch      = (const int*)d_in[2];
    const int*   num_entity = (const int*)d_in[3];
    const float* W1         = (const float*)d_in[4];
    const float* b1         = (const float*)d_in[5];
    const float* W2         = (const float*)d_in[6];
    const float* b2         = (const float*)d_in[7];
    const float* Wlin       = (const float*)d_in[8];
    const float* blin       = (const float*)d_in[9];
    float* out = (float*)d_out;

    int N = in_sizes[2];
    int E = in_sizes[1] / 2;
    int K = in_sizes[0] / N;      // 300
    int G = in_sizes[3];
    int NCLS = in_sizes[9];

    const int* row = ei;          // source
    const int* col = ei + E;      // target

    // ---- workspace layout ----
    char* wsb = (char*)d_ws;
    size_t off = 0;
    auto take = [&](size_t bytes) -> void* {
        void* p = wsb + off;
        off += (bytes + 255) & ~(size_t)255;
        return p;
    };
    int*   rowptr   = (int*)take((size_t)(N + 1) * 4);
    float* dinv     = (float*)take((size_t)N * 4);
    int*   bkt_cnt  = (int*)take(MAX_BKT * 4);
    int*   bkt_base = (int*)take((MAX_BKT + 1) * 4);
    int*   bcursor  = (int*)take(MAX_BKT * 4);
    int*   srcs     = (int*)take((size_t)E * 4);
    unsigned short* bufS = (unsigned short*)take((size_t)N * HID * 2);  // [N][64] fp16
    float* bufA     = (float*)take((size_t)N * HID * 4);                // fp32 h
    float* ent_sum  = (float*)take((size_t)G * HID * 4);
    float* all_sum  = (float*)take((size_t)G * HID * 4);
    float* ent_cnt  = (float*)take((size_t)G * 4);
    float* node_cnt = (float*)take((size_t)G * 4);

    // pairs (E*4 B) aliases bufS (N*HID*2 B, same size) — free until layer-1 gemm
    unsigned int* pairs = (unsigned int*)bufS;

    int nbkt = (N + BKT_W - 1) >> BKT_SHIFT;

    // ---- CSR build (bucketed) ----
    hipMemsetAsync(bkt_cnt, 0, (size_t)nbkt * 4, stream);
    k_bhist<<<(E + EPH - 1) / EPH, 256, 0, stream>>>(col, bkt_cnt, E, nbkt);
    k_bscan<<<1, 1, 0, stream>>>(bkt_cnt, bkt_base, bcursor, nbkt);
    k_binA<<<(E + EPB - 1) / EPB, 256, 0, stream>>>(row, col, bcursor, pairs, E, nbkt);
    k_binB<<<nbkt, 256, 0, stream>>>(pairs, bkt_base, rowptr, srcs, dinv, N, E);

    // ---- layer 1 ----
    k_gemm<<<(N + 63) / 64, 256, 0, stream>>>(x, W1, dinv, bufS, N, K);
    k_agg<<<(N + 3) / 4, 256, 0, stream>>>((const uint2*)bufS, rowptr, srcs,
                                           dinv, b1, bufA, N);
    // ---- layer 2 ----
    k_gemm<<<(N + 63) / 64, 256, 0, stream>>>(bufA, W2, dinv, bufS, N, HID);
    k_agg<<<(N + 3) / 4, 256, 0, stream>>>((const uint2*)bufS, rowptr, srcs,
                                           dinv, b2, bufA, N);

    // ---- pooling ----
    hipMemsetAsync(ent_sum, 0, ((size_t)2 * G * HID + 2 * G) * 4, stream);
    k_pool<<<(N + PCHUNK * 4 - 1) / (PCHUNK * 4), 256, 0, stream>>>(
        bufA, batch, num_entity, ent_sum, all_sum, ent_cnt, node_cnt, N);

    // ---- head ----
    k_final<<<G, HID, 0, stream>>>(ent_sum, all_sum, ent_cnt, node_cnt, Wlin, blin, out, NCLS);
}

// Round 15
// 410.559 us; speedup vs baseline: 1.8986x; 1.0155x over previous
//
#include <hip/hip_runtime.h>
#include <hip/hip_fp16.h>
#include <math.h>

#define HID 64
#define BKT_W 256
#define BKT_SHIFT 8
#define MAX_BKT 512        // supports N <= 131072
#define EPB 4096
#define EPH 16384

__device__ __forceinline__ unsigned int hadd2u(unsigned int a, unsigned int b) {
    __half2 r = __hadd2(*(__half2*)&a, *(__half2*)&b);
    return *(unsigned int*)&r;
}

// ---------------- bucket-level histogram ----------------
__global__ __launch_bounds__(256) void k_bhist(const int* __restrict__ col,
                                               int* __restrict__ bkt_cnt, int E, int nbkt) {
    __shared__ int h[MAX_BKT];
    int t = threadIdx.x;
    for (int b = t; b < nbkt; b += 256) h[b] = 0;
    __syncthreads();
    int e0 = blockIdx.x * EPH;
    int e1 = min(e0 + EPH, E);
    for (int e = e0 + t; e < e1; e += 256)
        atomicAdd(&h[col[e] >> BKT_SHIFT], 1);
    __syncthreads();
    for (int b = t; b < nbkt; b += 256)
        if (h[b]) atomicAdd(&bkt_cnt[b], h[b]);
}

// scan over buckets + cursor init (single thread; nbkt ~ 391)
__global__ void k_bscan(const int* __restrict__ bkt_cnt, int* __restrict__ bkt_base,
                        int* __restrict__ bcursor, int nbkt) {
    int run = 0;
    for (int b = 0; b < nbkt; ++b) {
        bkt_base[b] = run;
        bcursor[b] = run;
        run += bkt_cnt[b];
    }
    bkt_base[nbkt] = run;
}

// pass A: bin edges into bucket-contiguous packed (row<<8 | col&255) words
__global__ __launch_bounds__(256) void k_binA(const int* __restrict__ row,
                                              const int* __restrict__ col,
                                              int* __restrict__ bcursor,
                                              unsigned int* __restrict__ pairs,
                                              int E, int nbkt) {
    __shared__ int hist[MAX_BKT];
    __shared__ int base[MAX_BKT];
    int t = threadIdx.x;
    for (int b = t; b < nbkt; b += 256) hist[b] = 0;
    __syncthreads();
    int e0 = blockIdx.x * EPB;
    int myc[16], myr[16], myoff[16];
    #pragma unroll
    for (int i = 0; i < 16; ++i) {
        int e = e0 + t + i * 256;
        if (e < E) {
            myc[i] = col[e];
            myr[i] = row[e];
            myoff[i] = atomicAdd(&hist[myc[i] >> BKT_SHIFT], 1);
        }
    }
    __syncthreads();
    for (int b = t; b < nbkt; b += 256) {
        int h = hist[b];
        base[b] = h ? atomicAdd(&bcursor[b], h) : 0;
    }
    __syncthreads();
    #pragma unroll
    for (int i = 0; i < 16; ++i) {
        int e = e0 + t + i * 256;
        if (e < E) {
            int bk = myc[i] >> BKT_SHIFT;
            pairs[base[bk] + myoff[i]] =
                ((unsigned int)myr[i] << BKT_SHIFT) | (unsigned int)(myc[i] & (BKT_W - 1));
        }
    }
}

// pass B: per bucket — per-node counts in LDS, scan -> rowptr + dinv, scatter srcs
__global__ __launch_bounds__(256) void k_binB(const unsigned int* __restrict__ pairs,
                                              const int* __restrict__ bkt_base,
                                              int* __restrict__ rowptr,
                                              int* __restrict__ srcs,
                                              float* __restrict__ dinv,
                                              int n, int E) {
    __shared__ int cnt[BKT_W];
    __shared__ int s[BKT_W];
    __shared__ int lcur[BKT_W];
    int b = blockIdx.x, t = threadIdx.x;
    int n0 = b << BKT_SHIFT;
    int n1 = min(n0 + BKT_W, n);
    int s0 = bkt_base[b], s1 = bkt_base[b + 1];
    cnt[t] = 0;
    __syncthreads();
    for (int i = s0 + t; i < s1; i += 256)
        atomicAdd(&cnt[pairs[i] & (BKT_W - 1)], 1);
    __syncthreads();
    int v = cnt[t];
    s[t] = v;
    __syncthreads();
    #pragma unroll
    for (int off = 1; off < BKT_W; off <<= 1) {
        int tv = (t >= off) ? s[t - off] : 0;
        __syncthreads();
        s[t] += tv;
        __syncthreads();
    }
    int ex = s[t] - v;
    if (t < n1 - n0) {
        rowptr[n0 + t] = s0 + ex;
        dinv[n0 + t] = rsqrtf((float)(v + 1));   // +1 self-loop
    }
    lcur[t] = s0 + ex;
    __syncthreads();
    for (int i = s0 + t; i < s1; i += 256) {
        unsigned int p = pairs[i];
        int pos = atomicAdd(&lcur[p & (BKT_W - 1)], 1);
        srcs[pos] = (int)(p >> BKT_SHIFT);
    }
    if (n1 == n && t == 0) rowptr[n] = E;
}

// ---------------- GEMM: outH[i][c] = fp16( dinv[i] * (A@W)[i][c] ) ----------------
// 64x64 tile, BK=32, 256 threads, 4x4 micro-tile, register double-buffer prefetch:
// chunk t+1's global loads are issued before computing chunk t, so HBM latency
// (~900 cyc) hides under the ~1800-cyc compute phase.
#define SAP 68
__global__ __launch_bounds__(256) void k_gemm(const float* __restrict__ A,
                                              const float* __restrict__ W,
                                              const float* __restrict__ dinv,
                                              unsigned short* __restrict__ outH,
                                              int n, int K) {
    __shared__ float sA[32 * SAP];      // [kk][m] transposed
    __shared__ float sW[32 * SAP];      // [kk][c]
    int t = threadIdx.x;
    int m0 = blockIdx.x * 64;
    int tm = t >> 4, tn = t & 15;       // 4 rows x 4 cols per thread
    float acc[4][4] = {};

    int arow = t >> 2;                  // 0..63
    int akb  = (t & 3) * 8;             // 0,8,16,24
    int node = m0 + arow;

    int wr0 = t >> 4, wc40 = t & 15;            // W stage slot 0 (rows 0..15)
    int wr1 = (t + 256) >> 4, wc41 = t & 15;    // W stage slot 1 (rows 16..31)

    float4 ra0, ra1;                    // A prefetch regs (8 floats)
    float4 rw0, rw1;                    // W prefetch regs

    int nch = (K + 31) / 32;

    // ---- load chunk 0 ----
    {
        int k0 = 0;
        if (node < n && k0 + akb + 7 < K) {
            const float4* p = (const float4*)(A + (size_t)node * K + k0 + akb);
            ra0 = p[0]; ra1 = p[1];
        } else {
            float tmp[8];
            #pragma unroll
            for (int u = 0; u < 8; ++u) {
                int k = k0 + akb + u;
                tmp[u] = (node < n && k < K) ? A[(size_t)node * K + k] : 0.0f;
            }
            ra0 = {tmp[0], tmp[1], tmp[2], tmp[3]};
            ra1 = {tmp[4], tmp[5], tmp[6], tmp[7]};
        }
        float4 z = {0.f, 0.f, 0.f, 0.f};
        int ka = k0 + wr0;
        rw0 = (ka < K) ? *(const float4*)(W + (size_t)ka * HID + wc40 * 4) : z;
        int kb = k0 + wr1;
        rw1 = (kb < K) ? *(const float4*)(W + (size_t)kb * HID + wc41 * 4) : z;
    }

    for (int c = 0; c < nch; ++c) {
        // ---- store regs -> LDS ----
        sA[(akb + 0) * SAP + arow] = ra0.x;
        sA[(akb + 1) * SAP + arow] = ra0.y;
        sA[(akb + 2) * SAP + arow] = ra0.z;
        sA[(akb + 3) * SAP + arow] = ra0.w;
        sA[(akb + 4) * SAP + arow] = ra1.x;
        sA[(akb + 5) * SAP + arow] = ra1.y;
        sA[(akb + 6) * SAP + arow] = ra1.z;
        sA[(akb + 7) * SAP + arow] = ra1.w;
        *(float4*)&sW[wr0 * SAP + wc40 * 4] = rw0;
        *(float4*)&sW[wr1 * SAP + wc41 * 4] = rw1;
        __syncthreads();

        // ---- issue next chunk's global loads (stay in flight during compute) ----
        if (c + 1 < nch) {
            int k0 = (c + 1) * 32;
            if (node < n && k0 + akb + 7 < K) {
                const float4* p = (const float4*)(A + (size_t)node * K + k0 + akb);
                ra0 = p[0]; ra1 = p[1];
            } else {
                float tmp[8];
                #pragma unroll
                for (int u = 0; u < 8; ++u) {
                    int k = k0 + akb + u;
                    tmp[u] = (node < n && k < K) ? A[(size_t)node * K + k] : 0.0f;
                }
                ra0 = {tmp[0], tmp[1], tmp[2], tmp[3]};
                ra1 = {tmp[4], tmp[5], tmp[6], tmp[7]};
            }
            float4 z = {0.f, 0.f, 0.f, 0.f};
            int ka = k0 + wr0;
            rw0 = (ka < K) ? *(const float4*)(W + (size_t)ka * HID + wc40 * 4) : z;
            int kb = k0 + wr1;
            rw1 = (kb < K) ? *(const float4*)(W + (size_t)kb * HID + wc41 * 4) : z;
        }

        // ---- compute chunk c from LDS ----
        #pragma unroll
        for (int kk = 0; kk < 32; ++kk) {
            float4 av = *(const float4*)&sA[kk * SAP + tm * 4];
            float4 wv = *(const float4*)&sW[kk * SAP + tn * 4];
            const float* ap = &av.x;
            #pragma unroll
            for (int i = 0; i < 4; ++i) {
                float a = ap[i];
                acc[i][0] = fmaf(a, wv.x, acc[i][0]);
                acc[i][1] = fmaf(a, wv.y, acc[i][1]);
                acc[i][2] = fmaf(a, wv.z, acc[i][2]);
                acc[i][3] = fmaf(a, wv.w, acc[i][3]);
            }
        }
        __syncthreads();
    }

    #pragma unroll
    for (int i = 0; i < 4; ++i) {
        int onode = m0 + tm * 4 + i;
        if (onode < n) {
            float d = dinv[onode];
            float2 lo = {acc[i][0] * d, acc[i][1] * d};
            float2 hi = {acc[i][2] * d, acc[i][3] * d};
            __half2 h01 = __float22half2_rn(lo);
            __half2 h23 = __float22half2_rn(hi);
            uint2 o;
            o.x = *(unsigned int*)&h01;
            o.y = *(unsigned int*)&h23;
            *(uint2*)(outH + (size_t)onode * HID + tn * 4) = o;
        }
    }
}

// ---------------- gather aggregation (fp16 messages, packed adds) ----------------
// wave = 1 node. lane = e4*16 + c4: 16 lanes x uint2 (4 fp16 ch) cover the 64-ch row,
// 4 edges per gather instruction, 8 edges in flight. v_pk_add_f16 accumulate.
__global__ __launch_bounds__(256) void k_agg(const uint2* __restrict__ bp,
                                             const int* __restrict__ rowptr,
                                             const int* __restrict__ srcs,
                                             const float* __restrict__ dinv,
                                             const float* __restrict__ bias,
                                             float* __restrict__ out, int n) {
    int node = blockIdx.x * 4 + (threadIdx.x >> 6);
    if (node >= n) return;
    int lane = threadIdx.x & 63;
    int e4 = lane >> 4, c4 = lane & 15;
    unsigned int a01 = 0u, a23 = 0u;                   // half2 zeros
    if (e4 == 0) {                                     // self-loop term
        uint2 u = bp[(size_t)node * 16 + c4];
        a01 = u.x; a23 = u.y;
    }
    int s = rowptr[node], e = rowptr[node + 1];
    int k = s + e4;
    for (; k + 4 < e; k += 8) {
        int r0 = srcs[k];
        int r1 = srcs[k + 4];
        uint2 ua = bp[(size_t)r0 * 16 + c4];
        uint2 ub = bp[(size_t)r1 * 16 + c4];
        a01 = hadd2u(a01, ua.x);
        a23 = hadd2u(a23, ua.y);
        a01 = hadd2u(a01, ub.x);
        a23 = hadd2u(a23, ub.y);
    }
    if (k < e) {
        uint2 u = bp[(size_t)srcs[k] * 16 + c4];
        a01 = hadd2u(a01, u.x);
        a23 = hadd2u(a23, u.y);
    }
    a01 = hadd2u(a01, (unsigned int)__shfl_xor((int)a01, 16));
    a01 = hadd2u(a01, (unsigned int)__shfl_xor((int)a01, 32));
    a23 = hadd2u(a23, (unsigned int)__shfl_xor((int)a23, 16));
    a23 = hadd2u(a23, (unsigned int)__shfl_xor((int)a23, 32));
    if (lane < 16) {
        float d = dinv[node];
        float2 f01 = __half22float2(*(__half2*)&a01);
        float2 f23 = __half22float2(*(__half2*)&a23);
        float4 bs = *(const float4*)(bias + c4 * 4);
        float4 o;
        o.x = fmaf(f01.x, d, bs.x); o.x = o.x > 0.f ? o.x : 0.f;
        o.y = fmaf(f01.y, d, bs.y); o.y = o.y > 0.f ? o.y : 0.f;
        o.z = fmaf(f23.x, d, bs.z); o.z = o.z > 0.f ? o.z : 0.f;
        o.w = fmaf(f23.y, d, bs.w); o.w = o.w > 0.f ? o.w : 0.f;
        *(float4*)(out + (size_t)node * HID + c4 * 4) = o;
    }
}

// ---------------- pooling ----------------
#define PCHUNK 128
__global__ void k_pool(const float* __restrict__ h, const int* __restrict__ batch,
                       const int* __restrict__ ne_arr,
                       float* ent_sum, float* all_sum, float* ent_cnt, float* node_cnt,
                       int n) {
    int wave = blockIdx.x * (blockDim.x >> 6) + (threadIdx.x >> 6);
    int j = threadIdx.x & 63;
    int i0 = wave * PCHUNK;
    if (i0 >= n) return;
    int iend = min(i0 + PCHUNK, n);
    int g = batch[i0];
    int ne = ne_arr[g];
    float ea = 0.f, aa = 0.f, ec = 0.f, nc = 0.f;
    for (int i = i0; i < iend; ++i) {
        int gi = batch[i];
        if (gi != g) {
            atomicAdd(&all_sum[g * HID + j], aa);
            atomicAdd(&ent_sum[g * HID + j], ea);
            if (j == 0) { atomicAdd(&node_cnt[g], nc); atomicAdd(&ent_cnt[g], ec); }
            g = gi; ne = ne_arr[g];
            ea = aa = ec = nc = 0.f;
        }
        float v = h[(size_t)i * HID + j];
        aa += v; nc += 1.f;
        if (i < ne) { ea += v; ec += 1.f; }
    }
    atomicAdd(&all_sum[g * HID + j], aa);
    atomicAdd(&ent_sum[g * HID + j], ea);
    if (j == 0) { atomicAdd(&node_cnt[g], nc); atomicAdd(&ent_cnt[g], ec); }
}

// ---------------- head ----------------
__global__ void k_final(const float* __restrict__ ent_sum, const float* __restrict__ all_sum,
                        const float* __restrict__ ent_cnt, const float* __restrict__ node_cnt,
                        const float* __restrict__ Wlin, const float* __restrict__ blin,
                        float* __restrict__ out, int ncls) {
    int g = blockIdx.x, j = threadIdx.x;
    __shared__ float pooled[HID];
    __shared__ float logits[32];
    float ec = ent_cnt[g];
    float p;
    if (ec > 0.0f)
        p = ent_sum[g * HID + j] / (ec + 1e-6f);
    else
        p = all_sum[g * HID + j] / node_cnt[g];
    pooled[j] = p;
    __syncthreads();
    if (j < ncls) {
        float acc = blin[j];
        for (int k = 0; k < HID; ++k)
            acc = fmaf(pooled[k], Wlin[k * ncls + j], acc);
        logits[j] = acc;
    }
    __syncthreads();
    if (j < ncls) {
        float m = -INFINITY;
        for (int c = 0; c < ncls; ++c) m = fmaxf(m, logits[c]);
        float s = 0.0f;
        for (int c = 0; c < ncls; ++c) s += expf(logits[c] - m);
        out[g * ncls + j] = logits[j] - m - logf(s);
    }
}

extern "C" void kernel_launch(void* const* d_in, const int* in_sizes, int n_in,
                              void* d_out, int out_size, void* d_ws, size_t ws_size,
                              hipStream_t stream) {
    const float* x          = (const float*)d_in[0];
    const int*   ei         = (const int*)d_in[1];
    const int*   batch      = (const int*)d_in[2];
    const int*   num_entity = (const int*)d_in[3];
    const float* W1         = (const float*)d_in[4];
    const float* b1         = (const float*)d_in[5];
    const float* W2         = (const float*)d_in[6];
    const float* b2         = (const float*)d_in[7];
    const float* Wlin       = (const float*)d_in[8];
    const float* blin       = (const float*)d_in[9];
    float* out = (float*)d_out;

    int N = in_sizes[2];
    int E = in_sizes[1] / 2;
    int K = in_sizes[0] / N;      // 300
    int G = in_sizes[3];
    int NCLS = in_sizes[9];

    const int* row = ei;          // source
    const int* col = ei + E;      // target

    // ---- workspace layout ----
    char* wsb = (char*)d_ws;
    size_t off = 0;
    auto take = [&](size_t bytes) -> void* {
        void* p = wsb + off;
        off += (bytes + 255) & ~(size_t)255;
        return p;
    };
    int*   rowptr   = (int*)take((size_t)(N + 1) * 4);
    float* dinv     = (float*)take((size_t)N * 4);
    int*   bkt_cnt  = (int*)take(MAX_BKT * 4);
    int*   bkt_base = (int*)take((MAX_BKT + 1) * 4);
    int*   bcursor  = (int*)take(MAX_BKT * 4);
    int*   srcs     = (int*)take((size_t)E * 4);
    unsigned short* bufS = (unsigned short*)take((size_t)N * HID * 2);  // [N][64] fp16
    float* bufA     = (float*)take((size_t)N * HID * 4);                // fp32 h
    float* ent_sum  = (float*)take((size_t)G * HID * 4);
    float* all_sum  = (float*)take((size_t)G * HID * 4);
    float* ent_cnt  = (float*)take((size_t)G * 4);
    float* node_cnt = (float*)take((size_t)G * 4);

    // pairs (E*4 B) aliases bufS (N*HID*2 B, same size) — free until layer-1 gemm
    unsigned int* pairs = (unsigned int*)bufS;

    int nbkt = (N + BKT_W - 1) >> BKT_SHIFT;

    // ---- CSR build (bucketed) ----
    hipMemsetAsync(bkt_cnt, 0, (size_t)nbkt * 4, stream);
    k_bhist<<<(E + EPH - 1) / EPH, 256, 0, stream>>>(col, bkt_cnt, E, nbkt);
    k_bscan<<<1, 1, 0, stream>>>(bkt_cnt, bkt_base, bcursor, nbkt);
    k_binA<<<(E + EPB - 1) / EPB, 256, 0, stream>>>(row, col, bcursor, pairs, E, nbkt);
    k_binB<<<nbkt, 256, 0, stream>>>(pairs, bkt_base, rowptr, srcs, dinv, N, E);

    // ---- layer 1 ----
    k_gemm<<<(N + 63) / 64, 256, 0, stream>>>(x, W1, dinv, bufS, N, K);
    k_agg<<<(N + 3) / 4, 256, 0, stream>>>((const uint2*)bufS, rowptr, srcs,
                                           dinv, b1, bufA, N);
    // ---- layer 2 ----
    k_gemm<<<(N + 63) / 64, 256, 0, stream>>>(bufA, W2, dinv, bufS, N, HID);
    k_agg<<<(N + 3) / 4, 256, 0, stream>>>((const uint2*)bufS, rowptr, srcs,
                                           dinv, b2, bufA, N);

    // ---- pooling ----
    hipMemsetAsync(ent_sum, 0, ((size_t)2 * G * HID + 2 * G) * 4, stream);
    k_pool<<<(N + PCHUNK * 4 - 1) / (PCHUNK * 4), 256, 0, stream>>>(
        bufA, batch, num_entity, ent_sum, all_sum, ent_cnt, node_cnt, N);

    // ---- head ----
    k_final<<<G, HID, 0, stream>>>(ent_sum, all_sum, ent_cnt, node_cnt, Wlin, blin, out, NCLS);
}

// Round 16
// 362.997 us; speedup vs baseline: 2.1473x; 1.1310x over previous
//
#include <hip/hip_runtime.h>
#include <hip/hip_fp16.h>
#include <math.h>

#define HID 64
#define BKT_W 256
#define BKT_SHIFT 8
#define MAX_BKT 512        // supports N <= 131072
#define EPB 4096
#define EPH 16384

typedef __attribute__((ext_vector_type(8))) short short8v;
typedef __attribute__((ext_vector_type(4))) float float4v;

__device__ __forceinline__ unsigned short f2bf(float x) {
    unsigned int b = __float_as_uint(x);
    unsigned int r = (b + 0x7FFFu + ((b >> 16) & 1u)) >> 16;   // RNE
    return (unsigned short)r;
}

__device__ __forceinline__ unsigned int hadd2u(unsigned int a, unsigned int b) {
    __half2 r = __hadd2(*(__half2*)&a, *(__half2*)&b);
    return *(unsigned int*)&r;
}

// ---------------- bucket-level histogram ----------------
__global__ __launch_bounds__(256) void k_bhist(const int* __restrict__ col,
                                               int* __restrict__ bkt_cnt, int E, int nbkt) {
    __shared__ int h[MAX_BKT];
    int t = threadIdx.x;
    for (int b = t; b < nbkt; b += 256) h[b] = 0;
    __syncthreads();
    int e0 = blockIdx.x * EPH;
    int e1 = min(e0 + EPH, E);
    for (int e = e0 + t; e < e1; e += 256)
        atomicAdd(&h[col[e] >> BKT_SHIFT], 1);
    __syncthreads();
    for (int b = t; b < nbkt; b += 256)
        if (h[b]) atomicAdd(&bkt_cnt[b], h[b]);
}

// scan over buckets + cursor init (single thread; nbkt ~ 391)
__global__ void k_bscan(const int* __restrict__ bkt_cnt, int* __restrict__ bkt_base,
                        int* __restrict__ bcursor, int nbkt) {
    int run = 0;
    for (int b = 0; b < nbkt; ++b) {
        bkt_base[b] = run;
        bcursor[b] = run;
        run += bkt_cnt[b];
    }
    bkt_base[nbkt] = run;
}

// pass A: bin edges into bucket-contiguous packed (row<<8 | col&255) words
__global__ __launch_bounds__(256) void k_binA(const int* __restrict__ row,
                                              const int* __restrict__ col,
                                              int* __restrict__ bcursor,
                                              unsigned int* __restrict__ pairs,
                                              int E, int nbkt) {
    __shared__ int hist[MAX_BKT];
    __shared__ int base[MAX_BKT];
    int t = threadIdx.x;
    for (int b = t; b < nbkt; b += 256) hist[b] = 0;
    __syncthreads();
    int e0 = blockIdx.x * EPB;
    int myc[16], myr[16], myoff[16];
    #pragma unroll
    for (int i = 0; i < 16; ++i) {
        int e = e0 + t + i * 256;
        if (e < E) {
            myc[i] = col[e];
            myr[i] = row[e];
            myoff[i] = atomicAdd(&hist[myc[i] >> BKT_SHIFT], 1);
        }
    }
    __syncthreads();
    for (int b = t; b < nbkt; b += 256) {
        int h = hist[b];
        base[b] = h ? atomicAdd(&bcursor[b], h) : 0;
    }
    __syncthreads();
    #pragma unroll
    for (int i = 0; i < 16; ++i) {
        int e = e0 + t + i * 256;
        if (e < E) {
            int bk = myc[i] >> BKT_SHIFT;
            pairs[base[bk] + myoff[i]] =
                ((unsigned int)myr[i] << BKT_SHIFT) | (unsigned int)(myc[i] & (BKT_W - 1));
        }
    }
}

// pass B: per bucket — per-node counts in LDS, scan -> rowptr + dinv, scatter srcs
__global__ __launch_bounds__(256) void k_binB(const unsigned int* __restrict__ pairs,
                                              const int* __restrict__ bkt_base,
                                              int* __restrict__ rowptr,
                                              int* __restrict__ srcs,
                                              float* __restrict__ dinv,
                                              int n, int E) {
    __shared__ int cnt[BKT_W];
    __shared__ int s[BKT_W];
    __shared__ int lcur[BKT_W];
    int b = blockIdx.x, t = threadIdx.x;
    int n0 = b << BKT_SHIFT;
    int n1 = min(n0 + BKT_W, n);
    int s0 = bkt_base[b], s1 = bkt_base[b + 1];
    cnt[t] = 0;
    __syncthreads();
    for (int i = s0 + t; i < s1; i += 256)
        atomicAdd(&cnt[pairs[i] & (BKT_W - 1)], 1);
    __syncthreads();
    int v = cnt[t];
    s[t] = v;
    __syncthreads();
    #pragma unroll
    for (int off = 1; off < BKT_W; off <<= 1) {
        int tv = (t >= off) ? s[t - off] : 0;
        __syncthreads();
        s[t] += tv;
        __syncthreads();
    }
    int ex = s[t] - v;
    if (t < n1 - n0) {
        rowptr[n0 + t] = s0 + ex;
        dinv[n0 + t] = rsqrtf((float)(v + 1));   // +1 self-loop
    }
    lcur[t] = s0 + ex;
    __syncthreads();
    for (int i = s0 + t; i < s1; i += 256) {
        unsigned int p = pairs[i];
        int pos = atomicAdd(&lcur[p & (BKT_W - 1)], 1);
        srcs[pos] = (int)(p >> BKT_SHIFT);
    }
    if (n1 == n && t == 0) rowptr[n] = E;
}

// ---------------- W -> fragment-order bf16 (one-time per call) ----------------
// slot s = (kb*4 + p)*64 + l ; elem j: k = kb*32 + (j<4 ? g*4+j : 16+g*4+j-4),
// col = p*16 + (l&15), g = l>>4. Zero-padded for k >= K.
__global__ void k_wswz(const float* __restrict__ W, unsigned short* __restrict__ out,
                       int K, int nslots) {
    int s = blockIdx.x * blockDim.x + threadIdx.x;
    if (s >= nslots) return;
    int kb = s >> 8;
    int p = (s >> 6) & 3;
    int l = s & 63;
    int g = l >> 4, li = l & 15;
    int colc = p * 16 + li;
    unsigned short vals[8];
    #pragma unroll
    for (int j = 0; j < 8; ++j) {
        int k = kb * 32 + ((j < 4) ? (g * 4 + j) : (16 + g * 4 + j - 4));
        vals[j] = (k < K) ? f2bf(W[(size_t)k * HID + colc]) : (unsigned short)0;
    }
    ushort4* o = (ushort4*)(out + (size_t)s * 8);
    o[0] = make_ushort4(vals[0], vals[1], vals[2], vals[3]);
    o[1] = make_ushort4(vals[4], vals[5], vals[6], vals[7]);
}

// ---------------- MFMA GEMM: outH[i][c] = fp16( dinv[i] * (A@W)[i][c] ) ----------------
// 64x64 tile, 4 waves; wave w owns rows w*16..w*16+15, all 4 col-panels.
// A-frag straight from global fp32 (2x float4/lane, 64B/row coalesced) + cvt bf16;
// B-frag one 16B coalesced load from fragment-order Wswz (L2-hot). No LDS, no barriers.
__global__ __launch_bounds__(256) void k_gemm_mfma(const float* __restrict__ A,
                                                   const unsigned short* __restrict__ Wswz,
                                                   const float* __restrict__ dinv,
                                                   unsigned short* __restrict__ outH,
                                                   int n, int K) {
    int t = threadIdx.x;
    int w = t >> 6, l = t & 63;
    int g = l >> 4, li = l & 15;
    int m0 = blockIdx.x * 64;
    int node = m0 + w * 16 + li;
    const float* arow = A + (size_t)node * K;
    float4v acc0 = {0.f, 0.f, 0.f, 0.f};
    float4v acc1 = {0.f, 0.f, 0.f, 0.f};
    float4v acc2 = {0.f, 0.f, 0.f, 0.f};
    float4v acc3 = {0.f, 0.f, 0.f, 0.f};
    int KB = (K + 31) / 32;
    bool nok = node < n;

    for (int kb = 0; kb < KB; ++kb) {
        int k0 = kb * 32 + g * 4;
        float4 va = {0.f, 0.f, 0.f, 0.f};
        float4 vb = {0.f, 0.f, 0.f, 0.f};
        if (nok && k0 < K)      va = *(const float4*)(arow + k0);        // K%4==0 -> full
        if (nok && k0 + 16 < K) vb = *(const float4*)(arow + k0 + 16);
        short8v a;
        a[0] = (short)f2bf(va.x); a[1] = (short)f2bf(va.y);
        a[2] = (short)f2bf(va.z); a[3] = (short)f2bf(va.w);
        a[4] = (short)f2bf(vb.x); a[5] = (short)f2bf(vb.y);
        a[6] = (short)f2bf(vb.z); a[7] = (short)f2bf(vb.w);
        const short8v* wp = (const short8v*)(Wswz + (size_t)(kb * 4) * 64 * 8);
        short8v b0 = wp[0 * 64 + l];
        short8v b1 = wp[1 * 64 + l];
        short8v b2 = wp[2 * 64 + l];
        short8v b3 = wp[3 * 64 + l];
        acc0 = __builtin_amdgcn_mfma_f32_16x16x32_bf16(a, b0, acc0, 0, 0, 0);
        acc1 = __builtin_amdgcn_mfma_f32_16x16x32_bf16(a, b1, acc1, 0, 0, 0);
        acc2 = __builtin_amdgcn_mfma_f32_16x16x32_bf16(a, b2, acc2, 0, 0, 0);
        acc3 = __builtin_amdgcn_mfma_f32_16x16x32_bf16(a, b3, acc3, 0, 0, 0);
    }

    // C/D: col = lane&15 (within panel), row = (lane>>4)*4 + reg   [m89-verified]
    float dv[4];
    int rbase = m0 + w * 16 + g * 4;
    #pragma unroll
    for (int r = 0; r < 4; ++r)
        dv[r] = (rbase + r < n) ? dinv[rbase + r] : 0.f;
    #pragma unroll
    for (int r = 0; r < 4; ++r) {
        int rown = rbase + r;
        if (rown < n) {
            size_t ob = (size_t)rown * HID + li;
            float v0 = acc0[r] * dv[r];
            float v1 = acc1[r] * dv[r];
            float v2 = acc2[r] * dv[r];
            float v3 = acc3[r] * dv[r];
            __half h0 = __float2half(v0), h1 = __float2half(v1);
            __half h2 = __float2half(v2), h3 = __float2half(v3);
            outH[ob]      = *(unsigned short*)&h0;
            outH[ob + 16] = *(unsigned short*)&h1;
            outH[ob + 32] = *(unsigned short*)&h2;
            outH[ob + 48] = *(unsigned short*)&h3;
        }
    }
}

// ---------------- gather aggregation (fp16 messages, packed adds, 16 edges in flight) ----
__global__ __launch_bounds__(256) void k_agg(const uint2* __restrict__ bp,
                                             const int* __restrict__ rowptr,
                                             const int* __restrict__ srcs,
                                             const float* __restrict__ dinv,
                                             const float* __restrict__ bias,
                                             float* __restrict__ out, int n) {
    int node = blockIdx.x * 4 + (threadIdx.x >> 6);
    if (node >= n) return;
    int lane = threadIdx.x & 63;
    int e4 = lane >> 4, c4 = lane & 15;
    unsigned int a01 = 0u, a23 = 0u;                   // half2 zeros
    if (e4 == 0) {                                     // self-loop term
        uint2 u = bp[(size_t)node * 16 + c4];
        a01 = u.x; a23 = u.y;
    }
    int s = rowptr[node], e = rowptr[node + 1];
    int k = s + e4;
    for (; k + 12 < e; k += 16) {
        int r0 = srcs[k], r1 = srcs[k + 4], r2 = srcs[k + 8], r3 = srcs[k + 12];
        uint2 u0 = bp[(size_t)r0 * 16 + c4];
        uint2 u1 = bp[(size_t)r1 * 16 + c4];
        uint2 u2 = bp[(size_t)r2 * 16 + c4];
        uint2 u3 = bp[(size_t)r3 * 16 + c4];
        a01 = hadd2u(a01, u0.x); a23 = hadd2u(a23, u0.y);
        a01 = hadd2u(a01, u1.x); a23 = hadd2u(a23, u1.y);
        a01 = hadd2u(a01, u2.x); a23 = hadd2u(a23, u2.y);
        a01 = hadd2u(a01, u3.x); a23 = hadd2u(a23, u3.y);
    }
    for (; k < e; k += 4) {
        uint2 u = bp[(size_t)srcs[k] * 16 + c4];
        a01 = hadd2u(a01, u.x);
        a23 = hadd2u(a23, u.y);
    }
    a01 = hadd2u(a01, (unsigned int)__shfl_xor((int)a01, 16));
    a01 = hadd2u(a01, (unsigned int)__shfl_xor((int)a01, 32));
    a23 = hadd2u(a23, (unsigned int)__shfl_xor((int)a23, 16));
    a23 = hadd2u(a23, (unsigned int)__shfl_xor((int)a23, 32));
    if (lane < 16) {
        float d = dinv[node];
        float2 f01 = __half22float2(*(__half2*)&a01);
        float2 f23 = __half22float2(*(__half2*)&a23);
        float4 bs = *(const float4*)(bias + c4 * 4);
        float4 o;
        o.x = fmaf(f01.x, d, bs.x); o.x = o.x > 0.f ? o.x : 0.f;
        o.y = fmaf(f01.y, d, bs.y); o.y = o.y > 0.f ? o.y : 0.f;
        o.z = fmaf(f23.x, d, bs.z); o.z = o.z > 0.f ? o.z : 0.f;
        o.w = fmaf(f23.y, d, bs.w); o.w = o.w > 0.f ? o.w : 0.f;
        *(float4*)(out + (size_t)node * HID + c4 * 4) = o;
    }
}

// ---------------- pooling ----------------
#define PCHUNK 128
__global__ void k_pool(const float* __restrict__ h, const int* __restrict__ batch,
                       const int* __restrict__ ne_arr,
                       float* ent_sum, float* all_sum, float* ent_cnt, float* node_cnt,
                       int n) {
    int wave = blockIdx.x * (blockDim.x >> 6) + (threadIdx.x >> 6);
    int j = threadIdx.x & 63;
    int i0 = wave * PCHUNK;
    if (i0 >= n) return;
    int iend = min(i0 + PCHUNK, n);
    int g = batch[i0];
    int ne = ne_arr[g];
    float ea = 0.f, aa = 0.f, ec = 0.f, nc = 0.f;
    for (int i = i0; i < iend; ++i) {
        int gi = batch[i];
        if (gi != g) {
            atomicAdd(&all_sum[g * HID + j], aa);
            atomicAdd(&ent_sum[g * HID + j], ea);
            if (j == 0) { atomicAdd(&node_cnt[g], nc); atomicAdd(&ent_cnt[g], ec); }
            g = gi; ne = ne_arr[g];
            ea = aa = ec = nc = 0.f;
        }
        float v = h[(size_t)i * HID + j];
        aa += v; nc += 1.f;
        if (i < ne) { ea += v; ec += 1.f; }
    }
    atomicAdd(&all_sum[g * HID + j], aa);
    atomicAdd(&ent_sum[g * HID + j], ea);
    if (j == 0) { atomicAdd(&node_cnt[g], nc); atomicAdd(&ent_cnt[g], ec); }
}

// ---------------- head ----------------
__global__ void k_final(const float* __restrict__ ent_sum, const float* __restrict__ all_sum,
                        const float* __restrict__ ent_cnt, const float* __restrict__ node_cnt,
                        const float* __restrict__ Wlin, const float* __restrict__ blin,
                        float* __restrict__ out, int ncls) {
    int g = blockIdx.x, j = threadIdx.x;
    __shared__ float pooled[HID];
    __shared__ float logits[32];
    float ec = ent_cnt[g];
    float p;
    if (ec > 0.0f)
        p = ent_sum[g * HID + j] / (ec + 1e-6f);
    else
        p = all_sum[g * HID + j] / node_cnt[g];
    pooled[j] = p;
    __syncthreads();
    if (j < ncls) {
        float acc = blin[j];
        for (int k = 0; k < HID; ++k)
            acc = fmaf(pooled[k], Wlin[k * ncls + j], acc);
        logits[j] = acc;
    }
    __syncthreads();
    if (j < ncls) {
        float m = -INFINITY;
        for (int c = 0; c < ncls; ++c) m = fmaxf(m, logits[c]);
        float s = 0.0f;
        for (int c = 0; c < ncls; ++c) s += expf(logits[c] - m);
        out[g * ncls + j] = logits[j] - m - logf(s);
    }
}

extern "C" void kernel_launch(void* const* d_in, const int* in_sizes, int n_in,
                              void* d_out, int out_size, void* d_ws, size_t ws_size,
                              hipStream_t stream) {
    const float* x          = (const float*)d_in[0];
    const int*   ei         = (const int*)d_in[1];
    const int*   batch      = (const int*)d_in[2];
    const int*   num_entity = (const int*)d_in[3];
    const float* W1         = (const float*)d_in[4];
    const float* b1         = (const float*)d_in[5];
    const float* W2         = (const float*)d_in[6];
    const float* b2         = (const float*)d_in[7];
    const float* Wlin       = (const float*)d_in[8];
    const float* blin       = (const float*)d_in[9];
    float* out = (float*)d_out;

    int N = in_sizes[2];
    int E = in_sizes[1] / 2;
    int K = in_sizes[0] / N;      // 300
    int G = in_sizes[3];
    int NCLS = in_sizes[9];

    const int* row = ei;          // source
    const int* col = ei + E;      // target

    int KB1 = (K + 31) / 32;      // 10
    int KB2 = (HID + 31) / 32;    // 2
    int nslots1 = KB1 * 4 * 64;
    int nslots2 = KB2 * 4 * 64;

    // ---- workspace layout ----
    char* wsb = (char*)d_ws;
    size_t off = 0;
    auto take = [&](size_t bytes) -> void* {
        void* p = wsb + off;
        off += (bytes + 255) & ~(size_t)255;
        return p;
    };
    int*   rowptr   = (int*)take((size_t)(N + 1) * 4);
    float* dinv     = (float*)take((size_t)N * 4);
    int*   bkt_cnt  = (int*)take(MAX_BKT * 4);
    int*   bkt_base = (int*)take((MAX_BKT + 1) * 4);
    int*   bcursor  = (int*)take(MAX_BKT * 4);
    unsigned short* w1s = (unsigned short*)take((size_t)nslots1 * 16);
    unsigned short* w2s = (unsigned short*)take((size_t)nslots2 * 16);
    int*   srcs     = (int*)take((size_t)E * 4);
    unsigned short* bufS = (unsigned short*)take((size_t)N * HID * 2);  // [N][64] fp16
    float* bufA     = (float*)take((size_t)N * HID * 4);                // fp32 h
    float* ent_sum  = (float*)take((size_t)G * HID * 4);
    float* all_sum  = (float*)take((size_t)G * HID * 4);
    float* ent_cnt  = (float*)take((size_t)G * 4);
    float* node_cnt = (float*)take((size_t)G * 4);

    // pairs (E*4 B) aliases bufS (N*HID*2 B, same size) — free until layer-1 gemm
    unsigned int* pairs = (unsigned int*)bufS;

    int nbkt = (N + BKT_W - 1) >> BKT_SHIFT;

    // ---- W fragment pre-transform (independent of CSR) ----
    k_wswz<<<(nslots1 + 255) / 256, 256, 0, stream>>>(W1, w1s, K, nslots1);
    k_wswz<<<(nslots2 + 255) / 256, 256, 0, stream>>>(W2, w2s, HID, nslots2);

    // ---- CSR build (bucketed) ----
    hipMemsetAsync(bkt_cnt, 0, (size_t)nbkt * 4, stream);
    k_bhist<<<(E + EPH - 1) / EPH, 256, 0, stream>>>(col, bkt_cnt, E, nbkt);
    k_bscan<<<1, 1, 0, stream>>>(bkt_cnt, bkt_base, bcursor, nbkt);
    k_binA<<<(E + EPB - 1) / EPB, 256, 0, stream>>>(row, col, bcursor, pairs, E, nbkt);
    k_binB<<<nbkt, 256, 0, stream>>>(pairs, bkt_base, rowptr, srcs, dinv, N, E);

    // ---- layer 1 ----
    k_gemm_mfma<<<(N + 63) / 64, 256, 0, stream>>>(x, w1s, dinv, bufS, N, K);
    k_agg<<<(N + 3) / 4, 256, 0, stream>>>((const uint2*)bufS, rowptr, srcs,
                                           dinv, b1, bufA, N);
    // ---- layer 2 ----
    k_gemm_mfma<<<(N + 63) / 64, 256, 0, stream>>>(bufA, w2s, dinv, bufS, N, HID);
    k_agg<<<(N + 3) / 4, 256, 0, stream>>>((const uint2*)bufS, rowptr, srcs,
                                           dinv, b2, bufA, N);

    // ---- pooling ----
    hipMemsetAsync(ent_sum, 0, ((size_t)2 * G * HID + 2 * G) * 4, stream);
    k_pool<<<(N + PCHUNK * 4 - 1) / (PCHUNK * 4), 256, 0, stream>>>(
        bufA, batch, num_entity, ent_sum, all_sum, ent_cnt, node_cnt, N);

    // ---- head ----
    k_final<<<G, HID, 0, stream>>>(ent_sum, all_sum, ent_cnt, node_cnt, Wlin, blin, out, NCLS);
}

// Round 17
// 350.520 us; speedup vs baseline: 2.2238x; 1.0356x over previous
//
#include <hip/hip_runtime.h>
#include <hip/hip_fp16.h>
#include <math.h>

#define HID 64
#define BKT_W 256
#define BKT_SHIFT 8
#define MAX_BKT 512        // supports N <= 131072
#define EPB 4096
#define EPH 16384

typedef __attribute__((ext_vector_type(8))) short short8v;
typedef __attribute__((ext_vector_type(4))) float float4v;

__device__ __forceinline__ unsigned short f2bf(float x) {
    unsigned int b = __float_as_uint(x);
    unsigned int r = (b + 0x7FFFu + ((b >> 16) & 1u)) >> 16;   // RNE
    return (unsigned short)r;
}

__device__ __forceinline__ unsigned int hadd2u(unsigned int a, unsigned int b) {
    __half2 r = __hadd2(*(__half2*)&a, *(__half2*)&b);
    return *(unsigned int*)&r;
}

// ---------------- bucket-level histogram ----------------
__global__ __launch_bounds__(256) void k_bhist(const int* __restrict__ col,
                                               int* __restrict__ bkt_cnt, int E, int nbkt) {
    __shared__ int h[MAX_BKT];
    int t = threadIdx.x;
    for (int b = t; b < nbkt; b += 256) h[b] = 0;
    __syncthreads();
    int e0 = blockIdx.x * EPH;
    int e1 = min(e0 + EPH, E);
    for (int e = e0 + t; e < e1; e += 256)
        atomicAdd(&h[col[e] >> BKT_SHIFT], 1);
    __syncthreads();
    for (int b = t; b < nbkt; b += 256)
        if (h[b]) atomicAdd(&bkt_cnt[b], h[b]);
}

// parallel scan over buckets + cursor init (one 512-thread block)
__global__ __launch_bounds__(MAX_BKT) void k_bscan(const int* __restrict__ bkt_cnt,
                                                   int* __restrict__ bkt_base,
                                                   int* __restrict__ bcursor, int nbkt) {
    __shared__ int s[MAX_BKT];
    int t = threadIdx.x;
    int v = (t < nbkt) ? bkt_cnt[t] : 0;
    s[t] = v;
    __syncthreads();
    #pragma unroll
    for (int off = 1; off < MAX_BKT; off <<= 1) {
        int tv = (t >= off) ? s[t - off] : 0;
        __syncthreads();
        s[t] += tv;
        __syncthreads();
    }
    if (t < nbkt) {
        int ex = s[t] - v;
        bkt_base[t] = ex;
        bcursor[t] = ex;
        if (t == nbkt - 1) bkt_base[nbkt] = s[t];
    }
}

// pass A: bin edges into bucket-contiguous packed (row<<8 | col&255) words
__global__ __launch_bounds__(256) void k_binA(const int* __restrict__ row,
                                              const int* __restrict__ col,
                                              int* __restrict__ bcursor,
                                              unsigned int* __restrict__ pairs,
                                              int E, int nbkt) {
    __shared__ int hist[MAX_BKT];
    __shared__ int base[MAX_BKT];
    int t = threadIdx.x;
    for (int b = t; b < nbkt; b += 256) hist[b] = 0;
    __syncthreads();
    int e0 = blockIdx.x * EPB;
    int myc[16], myr[16], myoff[16];
    #pragma unroll
    for (int q = 0; q < 4; ++q) {
        int eb = e0 + t * 4 + q * 1024;
        if (eb + 3 < E) {
            int4 cv = *(const int4*)(col + eb);
            int4 rv = *(const int4*)(row + eb);
            myc[q*4+0] = cv.x; myc[q*4+1] = cv.y; myc[q*4+2] = cv.z; myc[q*4+3] = cv.w;
            myr[q*4+0] = rv.x; myr[q*4+1] = rv.y; myr[q*4+2] = rv.z; myr[q*4+3] = rv.w;
        } else {
            #pragma unroll
            for (int u = 0; u < 4; ++u) {
                int e = eb + u;
                if (e < E) { myc[q*4+u] = col[e]; myr[q*4+u] = row[e]; }
                else       { myc[q*4+u] = -1; myr[q*4+u] = 0; }
            }
        }
        #pragma unroll
        for (int u = 0; u < 4; ++u) {
            int i = q * 4 + u;
            if (myc[i] >= 0)
                myoff[i] = atomicAdd(&hist[myc[i] >> BKT_SHIFT], 1);
        }
    }
    __syncthreads();
    for (int b = t; b < nbkt; b += 256) {
        int h = hist[b];
        base[b] = h ? atomicAdd(&bcursor[b], h) : 0;
    }
    __syncthreads();
    #pragma unroll
    for (int i = 0; i < 16; ++i) {
        if (myc[i] >= 0) {
            int bk = myc[i] >> BKT_SHIFT;
            pairs[base[bk] + myoff[i]] =
                ((unsigned int)myr[i] << BKT_SHIFT) | (unsigned int)(myc[i] & (BKT_W - 1));
        }
    }
}

// pass B: per bucket — per-node counts in LDS, scan -> rowptr + dinv, scatter srcs
__global__ __launch_bounds__(256) void k_binB(const unsigned int* __restrict__ pairs,
                                              const int* __restrict__ bkt_base,
                                              int* __restrict__ rowptr,
                                              int* __restrict__ srcs,
                                              float* __restrict__ dinv,
                                              int n, int E) {
    __shared__ int cnt[BKT_W];
    __shared__ int s[BKT_W];
    __shared__ int lcur[BKT_W];
    int b = blockIdx.x, t = threadIdx.x;
    int n0 = b << BKT_SHIFT;
    int n1 = min(n0 + BKT_W, n);
    int s0 = bkt_base[b], s1 = bkt_base[b + 1];
    cnt[t] = 0;
    __syncthreads();
    for (int i = s0 + t; i < s1; i += 256)
        atomicAdd(&cnt[pairs[i] & (BKT_W - 1)], 1);
    __syncthreads();
    int v = cnt[t];
    s[t] = v;
    __syncthreads();
    #pragma unroll
    for (int off = 1; off < BKT_W; off <<= 1) {
        int tv = (t >= off) ? s[t - off] : 0;
        __syncthreads();
        s[t] += tv;
        __syncthreads();
    }
    int ex = s[t] - v;
    if (t < n1 - n0) {
        rowptr[n0 + t] = s0 + ex;
        dinv[n0 + t] = rsqrtf((float)(v + 1));   // +1 self-loop
    }
    lcur[t] = s0 + ex;
    __syncthreads();
    for (int i = s0 + t; i < s1; i += 256) {
        unsigned int p = pairs[i];
        int pos = atomicAdd(&lcur[p & (BKT_W - 1)], 1);
        srcs[pos] = (int)(p >> BKT_SHIFT);
    }
    if (n1 == n && t == 0) rowptr[n] = E;
}

// ---------------- W -> fragment-order bf16 (one-time per call) ----------------
__global__ void k_wswz(const float* __restrict__ W, unsigned short* __restrict__ out,
                       int K, int nslots) {
    int s = blockIdx.x * blockDim.x + threadIdx.x;
    if (s >= nslots) return;
    int kb = s >> 8;
    int p = (s >> 6) & 3;
    int l = s & 63;
    int g = l >> 4, li = l & 15;
    int colc = p * 16 + li;
    unsigned short vals[8];
    #pragma unroll
    for (int j = 0; j < 8; ++j) {
        int k = kb * 32 + ((j < 4) ? (g * 4 + j) : (16 + g * 4 + j - 4));
        vals[j] = (k < K) ? f2bf(W[(size_t)k * HID + colc]) : (unsigned short)0;
    }
    ushort4* o = (ushort4*)(out + (size_t)s * 8);
    o[0] = make_ushort4(vals[0], vals[1], vals[2], vals[3]);
    o[1] = make_ushort4(vals[4], vals[5], vals[6], vals[7]);
}

// ---------------- MFMA GEMM (fp32 A input) ----------------
__global__ __launch_bounds__(256) void k_gemm_mfma(const float* __restrict__ A,
                                                   const unsigned short* __restrict__ Wswz,
                                                   const float* __restrict__ dinv,
                                                   unsigned short* __restrict__ outH,
                                                   int n, int K) {
    int t = threadIdx.x;
    int w = t >> 6, l = t & 63;
    int g = l >> 4, li = l & 15;
    int m0 = blockIdx.x * 64;
    int node = m0 + w * 16 + li;
    const float* arow = A + (size_t)node * K;
    float4v acc0 = {0.f,0.f,0.f,0.f}, acc1 = {0.f,0.f,0.f,0.f};
    float4v acc2 = {0.f,0.f,0.f,0.f}, acc3 = {0.f,0.f,0.f,0.f};
    int KB = (K + 31) / 32;
    bool nok = node < n;

    for (int kb = 0; kb < KB; ++kb) {
        int k0 = kb * 32 + g * 4;
        float4 va = {0.f,0.f,0.f,0.f};
        float4 vb = {0.f,0.f,0.f,0.f};
        if (nok && k0 < K)      va = *(const float4*)(arow + k0);
        if (nok && k0 + 16 < K) vb = *(const float4*)(arow + k0 + 16);
        short8v a;
        a[0] = (short)f2bf(va.x); a[1] = (short)f2bf(va.y);
        a[2] = (short)f2bf(va.z); a[3] = (short)f2bf(va.w);
        a[4] = (short)f2bf(vb.x); a[5] = (short)f2bf(vb.y);
        a[6] = (short)f2bf(vb.z); a[7] = (short)f2bf(vb.w);
        const short8v* wp = (const short8v*)(Wswz + (size_t)(kb * 4) * 64 * 8);
        short8v b0 = wp[0 * 64 + l];
        short8v b1 = wp[1 * 64 + l];
        short8v b2 = wp[2 * 64 + l];
        short8v b3 = wp[3 * 64 + l];
        acc0 = __builtin_amdgcn_mfma_f32_16x16x32_bf16(a, b0, acc0, 0, 0, 0);
        acc1 = __builtin_amdgcn_mfma_f32_16x16x32_bf16(a, b1, acc1, 0, 0, 0);
        acc2 = __builtin_amdgcn_mfma_f32_16x16x32_bf16(a, b2, acc2, 0, 0, 0);
        acc3 = __builtin_amdgcn_mfma_f32_16x16x32_bf16(a, b3, acc3, 0, 0, 0);
    }

    float dv[4];
    int rbase = m0 + w * 16 + g * 4;
    #pragma unroll
    for (int r = 0; r < 4; ++r)
        dv[r] = (rbase + r < n) ? dinv[rbase + r] : 0.f;
    #pragma unroll
    for (int r = 0; r < 4; ++r) {
        int rown = rbase + r;
        if (rown < n) {
            size_t ob = (size_t)rown * HID + li;
            __half h0 = __float2half(acc0[r] * dv[r]);
            __half h1 = __float2half(acc1[r] * dv[r]);
            __half h2 = __float2half(acc2[r] * dv[r]);
            __half h3 = __float2half(acc3[r] * dv[r]);
            outH[ob]      = *(unsigned short*)&h0;
            outH[ob + 16] = *(unsigned short*)&h1;
            outH[ob + 32] = *(unsigned short*)&h2;
            outH[ob + 48] = *(unsigned short*)&h3;
        }
    }
}

// ---------------- MFMA GEMM (fp16 A input) ----------------
__global__ __launch_bounds__(256) void k_gemm_mfma_h(const unsigned short* __restrict__ Ah,
                                                     const unsigned short* __restrict__ Wswz,
                                                     const float* __restrict__ dinv,
                                                     unsigned short* __restrict__ outH,
                                                     int n, int K) {
    int t = threadIdx.x;
    int w = t >> 6, l = t & 63;
    int g = l >> 4, li = l & 15;
    int m0 = blockIdx.x * 64;
    int node = m0 + w * 16 + li;
    const uint2* arow = (const uint2*)(Ah + (size_t)node * K);   // 4 halves per uint2
    float4v acc0 = {0.f,0.f,0.f,0.f}, acc1 = {0.f,0.f,0.f,0.f};
    float4v acc2 = {0.f,0.f,0.f,0.f}, acc3 = {0.f,0.f,0.f,0.f};
    int KB = (K + 31) / 32;
    bool nok = node < n;

    for (int kb = 0; kb < KB; ++kb) {
        int k0 = kb * 32 + g * 4;
        uint2 ua = {0u, 0u}, ub = {0u, 0u};
        if (nok && k0 < K)      ua = arow[k0 >> 2];
        if (nok && k0 + 16 < K) ub = arow[(k0 + 16) >> 2];
        float2 fa0 = __half22float2(*(__half2*)&ua.x);
        float2 fa1 = __half22float2(*(__half2*)&ua.y);
        float2 fb0 = __half22float2(*(__half2*)&ub.x);
        float2 fb1 = __half22float2(*(__half2*)&ub.y);
        short8v a;
        a[0] = (short)f2bf(fa0.x); a[1] = (short)f2bf(fa0.y);
        a[2] = (short)f2bf(fa1.x); a[3] = (short)f2bf(fa1.y);
        a[4] = (short)f2bf(fb0.x); a[5] = (short)f2bf(fb0.y);
        a[6] = (short)f2bf(fb1.x); a[7] = (short)f2bf(fb1.y);
        const short8v* wp = (const short8v*)(Wswz + (size_t)(kb * 4) * 64 * 8);
        short8v b0 = wp[0 * 64 + l];
        short8v b1 = wp[1 * 64 + l];
        short8v b2 = wp[2 * 64 + l];
        short8v b3 = wp[3 * 64 + l];
        acc0 = __builtin_amdgcn_mfma_f32_16x16x32_bf16(a, b0, acc0, 0, 0, 0);
        acc1 = __builtin_amdgcn_mfma_f32_16x16x32_bf16(a, b1, acc1, 0, 0, 0);
        acc2 = __builtin_amdgcn_mfma_f32_16x16x32_bf16(a, b2, acc2, 0, 0, 0);
        acc3 = __builtin_amdgcn_mfma_f32_16x16x32_bf16(a, b3, acc3, 0, 0, 0);
    }

    float dv[4];
    int rbase = m0 + w * 16 + g * 4;
    #pragma unroll
    for (int r = 0; r < 4; ++r)
        dv[r] = (rbase + r < n) ? dinv[rbase + r] : 0.f;
    #pragma unroll
    for (int r = 0; r < 4; ++r) {
        int rown = rbase + r;
        if (rown < n) {
            size_t ob = (size_t)rown * HID + li;
            __half h0 = __float2half(acc0[r] * dv[r]);
            __half h1 = __float2half(acc1[r] * dv[r]);
            __half h2 = __float2half(acc2[r] * dv[r]);
            __half h3 = __float2half(acc3[r] * dv[r]);
            outH[ob]      = *(unsigned short*)&h0;
            outH[ob + 16] = *(unsigned short*)&h1;
            outH[ob + 32] = *(unsigned short*)&h2;
            outH[ob + 48] = *(unsigned short*)&h3;
        }
    }
}

// ---------------- gather aggregation (fp16 msgs, predicated 16-edge body) ----------------
// wave = 1 node. lane = e4*16 + c4. Slots k+4/8/12 predicated (fallback = r0's line).
// out16 != null -> write fp16 row (layer 1); else fp32 to out32 (layer 2).
__global__ __launch_bounds__(256) void k_agg(const uint2* __restrict__ bp,
                                             const int* __restrict__ rowptr,
                                             const int* __restrict__ srcs,
                                             const float* __restrict__ dinv,
                                             const float* __restrict__ bias,
                                             float* __restrict__ out32,
                                             unsigned short* __restrict__ out16, int n) {
    int node = blockIdx.x * 4 + (threadIdx.x >> 6);
    if (node >= n) return;
    int lane = threadIdx.x & 63;
    int e4 = lane >> 4, c4 = lane & 15;
    unsigned int a01 = 0u, a23 = 0u;
    if (e4 == 0) {                                     // self-loop term
        uint2 u = bp[(size_t)node * 16 + c4];
        a01 = u.x; a23 = u.y;
    }
    int s = rowptr[node], e = rowptr[node + 1];
    for (int k = s + e4; k < e; k += 16) {
        int k1 = k + 4, k2 = k + 8, k3 = k + 12;
        int r0 = srcs[k];
        int r1 = (k1 < e) ? srcs[k1] : r0;
        int r2 = (k2 < e) ? srcs[k2] : r0;
        int r3 = (k3 < e) ? srcs[k3] : r0;
        uint2 u0 = bp[(size_t)r0 * 16 + c4];
        uint2 u1 = bp[(size_t)r1 * 16 + c4];
        uint2 u2 = bp[(size_t)r2 * 16 + c4];
        uint2 u3 = bp[(size_t)r3 * 16 + c4];
        a01 = hadd2u(a01, u0.x); a23 = hadd2u(a23, u0.y);
        if (k1 < e) { a01 = hadd2u(a01, u1.x); a23 = hadd2u(a23, u1.y); }
        if (k2 < e) { a01 = hadd2u(a01, u2.x); a23 = hadd2u(a23, u2.y); }
        if (k3 < e) { a01 = hadd2u(a01, u3.x); a23 = hadd2u(a23, u3.y); }
    }
    a01 = hadd2u(a01, (unsigned int)__shfl_xor((int)a01, 16));
    a01 = hadd2u(a01, (unsigned int)__shfl_xor((int)a01, 32));
    a23 = hadd2u(a23, (unsigned int)__shfl_xor((int)a23, 16));
    a23 = hadd2u(a23, (unsigned int)__shfl_xor((int)a23, 32));
    if (lane < 16) {
        float d = dinv[node];
        float2 f01 = __half22float2(*(__half2*)&a01);
        float2 f23 = __half22float2(*(__half2*)&a23);
        float4 bs = *(const float4*)(bias + c4 * 4);
        float4 o;
        o.x = fmaf(f01.x, d, bs.x); o.x = o.x > 0.f ? o.x : 0.f;
        o.y = fmaf(f01.y, d, bs.y); o.y = o.y > 0.f ? o.y : 0.f;
        o.z = fmaf(f23.x, d, bs.z); o.z = o.z > 0.f ? o.z : 0.f;
        o.w = fmaf(f23.y, d, bs.w); o.w = o.w > 0.f ? o.w : 0.f;
        if (out16) {
            __half2 h01 = __float22half2_rn(make_float2(o.x, o.y));
            __half2 h23 = __float22half2_rn(make_float2(o.z, o.w));
            uint2 ov;
            ov.x = *(unsigned int*)&h01;
            ov.y = *(unsigned int*)&h23;
            *(uint2*)(out16 + (size_t)node * HID + c4 * 4) = ov;
        } else {
            *(float4*)(out32 + (size_t)node * HID + c4 * 4) = o;
        }
    }
}

// ---------------- pooling ----------------
#define PCHUNK 128
__global__ void k_pool(const float* __restrict__ h, const int* __restrict__ batch,
                       const int* __restrict__ ne_arr,
                       float* ent_sum, float* all_sum, float* ent_cnt, float* node_cnt,
                       int n) {
    int wave = blockIdx.x * (blockDim.x >> 6) + (threadIdx.x >> 6);
    int j = threadIdx.x & 63;
    int i0 = wave * PCHUNK;
    if (i0 >= n) return;
    int iend = min(i0 + PCHUNK, n);
    int g = batch[i0];
    int ne = ne_arr[g];
    float ea = 0.f, aa = 0.f, ec = 0.f, nc = 0.f;
    for (int i = i0; i < iend; ++i) {
        int gi = batch[i];
        if (gi != g) {
            atomicAdd(&all_sum[g * HID + j], aa);
            atomicAdd(&ent_sum[g * HID + j], ea);
            if (j == 0) { atomicAdd(&node_cnt[g], nc); atomicAdd(&ent_cnt[g], ec); }
            g = gi; ne = ne_arr[g];
            ea = aa = ec = nc = 0.f;
        }
        float v = h[(size_t)i * HID + j];
        aa += v; nc += 1.f;
        if (i < ne) { ea += v; ec += 1.f; }
    }
    atomicAdd(&all_sum[g * HID + j], aa);
    atomicAdd(&ent_sum[g * HID + j], ea);
    if (j == 0) { atomicAdd(&node_cnt[g], nc); atomicAdd(&ent_cnt[g], ec); }
}

// ---------------- head ----------------
__global__ void k_final(const float* __restrict__ ent_sum, const float* __restrict__ all_sum,
                        const float* __restrict__ ent_cnt, const float* __restrict__ node_cnt,
                        const float* __restrict__ Wlin, const float* __restrict__ blin,
                        float* __restrict__ out, int ncls) {
    int g = blockIdx.x, j = threadIdx.x;
    __shared__ float pooled[HID];
    __shared__ float logits[32];
    float ec = ent_cnt[g];
    float p;
    if (ec > 0.0f)
        p = ent_sum[g * HID + j] / (ec + 1e-6f);
    else
        p = all_sum[g * HID + j] / node_cnt[g];
    pooled[j] = p;
    __syncthreads();
    if (j < ncls) {
        float acc = blin[j];
        for (int k = 0; k < HID; ++k)
            acc = fmaf(pooled[k], Wlin[k * ncls + j], acc);
        logits[j] = acc;
    }
    __syncthreads();
    if (j < ncls) {
        float m = -INFINITY;
        for (int c = 0; c < ncls; ++c) m = fmaxf(m, logits[c]);
        float s = 0.0f;
        for (int c = 0; c < ncls; ++c) s += expf(logits[c] - m);
        out[g * ncls + j] = logits[j] - m - logf(s);
    }
}

extern "C" void kernel_launch(void* const* d_in, const int* in_sizes, int n_in,
                              void* d_out, int out_size, void* d_ws, size_t ws_size,
                              hipStream_t stream) {
    const float* x          = (const float*)d_in[0];
    const int*   ei         = (const int*)d_in[1];
    const int*   batch      = (const int*)d_in[2];
    const int*   num_entity = (const int*)d_in[3];
    const float* W1         = (const float*)d_in[4];
    const float* b1         = (const float*)d_in[5];
    const float* W2         = (const float*)d_in[6];
    const float* b2         = (const float*)d_in[7];
    const float* Wlin       = (const float*)d_in[8];
    const float* blin       = (const float*)d_in[9];
    float* out = (float*)d_out;

    int N = in_sizes[2];
    int E = in_sizes[1] / 2;
    int K = in_sizes[0] / N;      // 300
    int G = in_sizes[3];
    int NCLS = in_sizes[9];

    const int* row = ei;          // source
    const int* col = ei + E;      // target

    int KB1 = (K + 31) / 32;      // 10
    int KB2 = (HID + 31) / 32;    // 2
    int nslots1 = KB1 * 4 * 64;
    int nslots2 = KB2 * 4 * 64;

    // ---- workspace layout ----
    char* wsb = (char*)d_ws;
    size_t off = 0;
    auto take = [&](size_t bytes) -> void* {
        void* p = wsb + off;
        off += (bytes + 255) & ~(size_t)255;
        return p;
    };
    int*   rowptr   = (int*)take((size_t)(N + 1) * 4);
    float* dinv     = (float*)take((size_t)N * 4);
    int*   bkt_cnt  = (int*)take(MAX_BKT * 4);
    int*   bkt_base = (int*)take((MAX_BKT + 1) * 4);
    int*   bcursor  = (int*)take(MAX_BKT * 4);
    unsigned short* w1s = (unsigned short*)take((size_t)nslots1 * 16);
    unsigned short* w2s = (unsigned short*)take((size_t)nslots2 * 16);
    int*   srcs     = (int*)take((size_t)E * 4);
    unsigned short* bufS = (unsigned short*)take((size_t)N * HID * 2);  // messages fp16
    unsigned short* bufH = (unsigned short*)take((size_t)N * HID * 2);  // h1 fp16
    float* bufA     = (float*)take((size_t)N * HID * 4);                // h2 fp32 (pool input)
    float* ent_sum  = (float*)take((size_t)G * HID * 4);
    float* all_sum  = (float*)take((size_t)G * HID * 4);
    float* ent_cnt  = (float*)take((size_t)G * 4);
    float* node_cnt = (float*)take((size_t)G * 4);

    // pairs (E*4 B) aliases bufS (N*HID*2 B, same size) — free until layer-1 gemm
    unsigned int* pairs = (unsigned int*)bufS;

    int nbkt = (N + BKT_W - 1) >> BKT_SHIFT;

    // ---- W fragment pre-transform (independent of CSR) ----
    k_wswz<<<(nslots1 + 255) / 256, 256, 0, stream>>>(W1, w1s, K, nslots1);
    k_wswz<<<(nslots2 + 255) / 256, 256, 0, stream>>>(W2, w2s, HID, nslots2);

    // ---- CSR build (bucketed) ----
    hipMemsetAsync(bkt_cnt, 0, (size_t)nbkt * 4, stream);
    k_bhist<<<(E + EPH - 1) / EPH, 256, 0, stream>>>(col, bkt_cnt, E, nbkt);
    k_bscan<<<1, MAX_BKT, 0, stream>>>(bkt_cnt, bkt_base, bcursor, nbkt);
    k_binA<<<(E + EPB - 1) / EPB, 256, 0, stream>>>(row, col, bcursor, pairs, E, nbkt);
    k_binB<<<nbkt, 256, 0, stream>>>(pairs, bkt_base, rowptr, srcs, dinv, N, E);

    // ---- layer 1 ----
    k_gemm_mfma<<<(N + 63) / 64, 256, 0, stream>>>(x, w1s, dinv, bufS, N, K);
    k_agg<<<(N + 3) / 4, 256, 0, stream>>>((const uint2*)bufS, rowptr, srcs,
                                           dinv, b1, nullptr, bufH, N);
    // ---- layer 2 ----
    k_gemm_mfma_h<<<(N + 63) / 64, 256, 0, stream>>>(bufH, w2s, dinv, bufS, N, HID);
    k_agg<<<(N + 3) / 4, 256, 0, stream>>>((const uint2*)bufS, rowptr, srcs,
                                           dinv, b2, bufA, nullptr, N);

    // ---- pooling ----
    hipMemsetAsync(ent_sum, 0, ((size_t)2 * G * HID + 2 * G) * 4, stream);
    k_pool<<<(N + PCHUNK * 4 - 1) / (PCHUNK * 4), 256, 0, stream>>>(
        bufA, batch, num_entity, ent_sum, all_sum, ent_cnt, node_cnt, N);

    // ---- head ----
    k_final<<<G, HID, 0, stream>>>(ent_sum, all_sum, ent_cnt, node_cnt, Wlin, blin, out, NCLS);
}